// Round 3
// baseline (1027.801 us; speedup 1.0000x reference)
//
#include <hip/hip_runtime.h>
#include <hip/hip_bf16.h>
#include <math.h>

#define B_TOTAL 131072
#define NX 64
#define H 512
#define LD 8
#define NT 45          // 1 + 8 + 36
#define NSTEPS 20

// ---- main MFMA kernel config ----
#define ROWS 32        // rows per block
#define NTH 512        // 8 waves
#define ASTR 520       // bf16 elems per act row (1040 B: 16B-aligned rows)

// ws layout: bf16 W^T sections, then fp32 eW3T
#define OFF_EW1T 0                    // [512][64] bf16
#define OFF_EW2T 32768                // [512][512] bf16
#define OFF_DW2T 294912               // [512][512] bf16
#define OFF_DW3T 557056               // [64][512] bf16
#define WS_BF16_ELEMS 589824
#define OFF_EW3T_F32 294912           // float index (= byte 1179648): [8][512] fp32
#define EW3T_ELEMS 4096
#define WS_BYTES (WS_BF16_ELEMS * 2 + EW3T_ELEMS * 4)

typedef __attribute__((ext_vector_type(8))) short short8;
typedef __attribute__((ext_vector_type(4))) float f32x4;

__device__ __forceinline__ ushort f2bf(float f) {
    union { float f; uint u; } v; v.f = f;
    uint u = v.u;
    u += 0x7fff + ((u >> 16) & 1);          // RNE
    return (ushort)(u >> 16);
}
__device__ __forceinline__ float bf2f(ushort s) {
    union { uint u; float f; } v; v.u = ((uint)s) << 16;
    return v.f;
}
__device__ __forceinline__ uint pkbf(float a, float b) {
    union { __hip_bfloat162 h; uint u; } v;
    v.h = __float22bfloat162_rn(make_float2(a, b));
    return v.u;
}
__device__ __forceinline__ float silu_f(float v) {
    return v / (1.0f + __expf(-v));
}

// ---------------- weight prep ----------------
__global__ void prep_weights(const float* __restrict__ eW1, const float* __restrict__ eW2,
                             const float* __restrict__ dW2, const float* __restrict__ dW3,
                             const float* __restrict__ eW3, void* __restrict__ wsv) {
    short* ws = (short*)wsv;
    float* wf = (float*)wsv;
    const int id = blockIdx.x * 256 + threadIdx.x;
    if (id < OFF_EW2T) {                               // eW1T[n][k], n<512, k<64
        const int n = id >> 6, k = id & 63;
        ws[id] = (short)f2bf(eW1[k * H + n]);
    } else if (id < OFF_DW2T) {                        // eW2T 512x512
        const int j = id - OFF_EW2T, n = j >> 9, k = j & 511;
        ws[id] = (short)f2bf(eW2[k * H + n]);
    } else if (id < OFF_DW3T) {                        // dW2T 512x512
        const int j = id - OFF_DW2T, n = j >> 9, k = j & 511;
        ws[id] = (short)f2bf(dW2[k * H + n]);
    } else if (id < WS_BF16_ELEMS) {                   // dW3T[n][k], n<64, k<512
        const int j = id - OFF_DW3T, n = j >> 9, k = j & 511;
        ws[id] = (short)f2bf(dW3[k * NX + n]);
    } else {                                           // eW3T fp32 [8][512]
        const int j = id - WS_BF16_ELEMS, n = j >> 9, k = j & 511;
        wf[OFF_EW3T_F32 + j] = eW3[k * LD + n];
    }
}

// ---------------- big GEMM: act[32][K] bf16 LDS @ WT bf16 global ----------------
template <int K>
__device__ __forceinline__ void gemm_mfma(const short (*act)[ASTR], const short* __restrict__ WT,
                                          f32x4 acc[2][4], int w, int lane) {
    const int lm = lane & 15, q = lane >> 4;
#pragma unroll 4
    for (int kc = 0; kc < K / 32; ++kc) {
        const int k0 = kc * 32 + q * 8;
        short8 a0 = *(const short8*)&act[lm][k0];
        short8 a1 = *(const short8*)&act[16 + lm][k0];
        short8 b0 = *(const short8*)&WT[(w * 64 + 0 * 16 + lm) * K + k0];
        short8 b1 = *(const short8*)&WT[(w * 64 + 1 * 16 + lm) * K + k0];
        short8 b2 = *(const short8*)&WT[(w * 64 + 2 * 16 + lm) * K + k0];
        short8 b3 = *(const short8*)&WT[(w * 64 + 3 * 16 + lm) * K + k0];
        acc[0][0] = __builtin_amdgcn_mfma_f32_16x16x32_bf16(a0, b0, acc[0][0], 0, 0, 0);
        acc[1][0] = __builtin_amdgcn_mfma_f32_16x16x32_bf16(a1, b0, acc[1][0], 0, 0, 0);
        acc[0][1] = __builtin_amdgcn_mfma_f32_16x16x32_bf16(a0, b1, acc[0][1], 0, 0, 0);
        acc[1][1] = __builtin_amdgcn_mfma_f32_16x16x32_bf16(a1, b1, acc[1][1], 0, 0, 0);
        acc[0][2] = __builtin_amdgcn_mfma_f32_16x16x32_bf16(a0, b2, acc[0][2], 0, 0, 0);
        acc[1][2] = __builtin_amdgcn_mfma_f32_16x16x32_bf16(a1, b2, acc[1][2], 0, 0, 0);
        acc[0][3] = __builtin_amdgcn_mfma_f32_16x16x32_bf16(a0, b3, acc[0][3], 0, 0, 0);
        acc[1][3] = __builtin_amdgcn_mfma_f32_16x16x32_bf16(a1, b3, acc[1][3], 0, 0, 0);
    }
}

__device__ __forceinline__ void zero_acc(f32x4 acc[2][4]) {
#pragma unroll
    for (int mt = 0; mt < 2; ++mt)
#pragma unroll
        for (int t = 0; t < 4; ++t) acc[mt][t] = (f32x4){0.f, 0.f, 0.f, 0.f};
}

// bias + LayerNorm + SiLU on C-layout accs, bf16 store IN PLACE into act.
// C-layout: value (row = mt*16 + q*4 + reg, col = w*64 + t*16 + lm).
__device__ __forceinline__ void ln_silu_store(f32x4 acc[2][4],
        const float* __restrict__ bias, const float* __restrict__ g, const float* __restrict__ be,
        short (*dst)[ASTR], float (*p1)[8], float (*p2)[8], float (*rstat)[2],
        int w, int lane, int tid) {
    const int lm = lane & 15, q = lane >> 4;
    float cb[4], cg[4], cbe[4];
#pragma unroll
    for (int t = 0; t < 4; ++t) {
        const int c = w * 64 + t * 16 + lm;
        cb[t] = bias[c]; cg[t] = g[c]; cbe[t] = be[c];
    }
    float s1[8], s2[8];
#pragma unroll
    for (int i = 0; i < 8; ++i) { s1[i] = 0.f; s2[i] = 0.f; }
#pragma unroll
    for (int mt = 0; mt < 2; ++mt)
#pragma unroll
        for (int t = 0; t < 4; ++t)
#pragma unroll
            for (int r = 0; r < 4; ++r) {
                float v = acc[mt][t][r] + cb[t];
                acc[mt][t][r] = v;
                s1[mt * 4 + r] += v;
                s2[mt * 4 + r] += v * v;
            }
#pragma unroll
    for (int m = 1; m < 16; m <<= 1) {
#pragma unroll
        for (int i = 0; i < 8; ++i) {
            s1[i] += __shfl_xor(s1[i], m);
            s2[i] += __shfl_xor(s2[i], m);
        }
    }
    if (lm == 0) {
#pragma unroll
        for (int i = 0; i < 8; ++i) {
            const int row = (i >> 2) * 16 + q * 4 + (i & 3);
            p1[row][w] = s1[i];
            p2[row][w] = s2[i];
        }
    }
    __syncthreads();     // also orders: all GEMM act reads done before writes below
    if (tid < ROWS) {
        float a = 0.f, b2 = 0.f;
#pragma unroll
        for (int j = 0; j < 8; ++j) { a += p1[tid][j]; b2 += p2[tid][j]; }
        const float mean = a * (1.0f / H);
        rstat[tid][0] = mean;
        rstat[tid][1] = rsqrtf(b2 * (1.0f / H) - mean * mean + 1e-5f);
    }
    __syncthreads();
#pragma unroll
    for (int mt = 0; mt < 2; ++mt) {
        const int rowb = mt * 16 + q * 4;
#pragma unroll
        for (int rp = 0; rp < 2; ++rp) {
            const int r0 = rp * 2;
            const float2 st0 = *(const float2*)rstat[rowb + r0];
            const float2 st1 = *(const float2*)rstat[rowb + r0 + 1];
#pragma unroll
            for (int t = 0; t < 4; ++t) {
                float v0 = (acc[mt][t][r0]     - st0.x) * st0.y * cg[t] + cbe[t];
                float v1 = (acc[mt][t][r0 + 1] - st1.x) * st1.y * cg[t] + cbe[t];
                const uint u = pkbf(silu_f(v0), silu_f(v1));
                const int col = w * 64 + t * 16 + lm;
                dst[rowb + r0][col]     = (short)(u & 0xffff);
                dst[rowb + r0 + 1][col] = (short)(u >> 16);
            }
        }
    }
    __syncthreads();
}

__global__ __launch_bounds__(NTH, 6) void sindy_mfma_kernel(
    const float* __restrict__ x0, const float* __restrict__ logdt,
    const float* __restrict__ eb1, const float* __restrict__ eg1, const float* __restrict__ ebe1,
    const float* __restrict__ eb2, const float* __restrict__ eg2, const float* __restrict__ ebe2,
    const float* __restrict__ eb3,
    const float* __restrict__ dW1, const float* __restrict__ db1,
    const float* __restrict__ dg1, const float* __restrict__ dbe1,
    const float* __restrict__ db2, const float* __restrict__ dg2, const float* __restrict__ dbe2,
    const float* __restrict__ db3, const float* __restrict__ Xi,
    const void* __restrict__ wsv, float* __restrict__ out) {
    __shared__ __align__(16) short act[ROWS][ASTR];
    __shared__ float part1[ROWS][8], part2[ROWS][8];
    __shared__ float rowstat[ROWS][2];
    __shared__ float zbuf[ROWS][LD];

    const int tid = threadIdx.x;
    const int w = tid >> 6, lane = tid & 63;
    const int lm = lane & 15, q = lane >> 4;
    const int row0 = blockIdx.x * ROWS;

    const short* wsb = (const short*)wsv;
    const float* wsf = (const float*)wsv;
    const short* eW1T = wsb + OFF_EW1T;
    const short* eW2T = wsb + OFF_EW2T;
    const short* dW2T = wsb + OFF_DW2T;
    const short* dW3T = wsb + OFF_DW3T;
    const float* eW3T = wsf + OFF_EW3T_F32;

    // ---- stage x tile (fp32 -> bf16 LDS, packed cvt) ----
    {
        const int r = tid >> 4, c4 = (tid & 15) * 4;
        const float4 v = *(const float4*)&x0[(row0 + r) * NX + c4];
        uint2 pv;
        pv.x = pkbf(v.x, v.y);
        pv.y = pkbf(v.z, v.w);
        *(uint2*)&act[r][c4] = pv;
    }
    __syncthreads();

    // ---- encoder layer 1: 64 -> 512 (MFMA), LN+SiLU in place ----
    {
        f32x4 acc[2][4];
        zero_acc(acc);
        gemm_mfma<NX>(act, eW1T, acc, w, lane);
        ln_silu_store(acc, eb1, eg1, ebe1, act, part1, part2, rowstat, w, lane, tid);
    }

    // ---- encoder layer 2: 512 -> 512 (MFMA), LN+SiLU in place ----
    {
        f32x4 acc[2][4];
        zero_acc(acc);
        gemm_mfma<H>(act, eW2T, acc, w, lane);
        ln_silu_store(acc, eb2, eg2, ebe2, act, part1, part2, rowstat, w, lane, tid);
    }

    // ---- encoder layer 3: 512 -> 8 (fp32 weights), tanh -> z0 ----
    // All 512 threads: (row, col, k-half); pairwise shfl combine.
    {
        const int r = tid >> 4, cc = (tid >> 1) & 7, hf = tid & 1;
        const float* wT = eW3T + cc * H + hf * 256;
        const short* arow = &act[r][hf * 256];
        float s = 0.f;
#pragma unroll 4
        for (int k = 0; k < 256; k += 8) {
            short8 hv = *(const short8*)&arow[k];
            float4 w0 = *(const float4*)&wT[k];
            float4 w1 = *(const float4*)&wT[k + 4];
            s += bf2f((ushort)hv[0]) * w0.x + bf2f((ushort)hv[1]) * w0.y +
                 bf2f((ushort)hv[2]) * w0.z + bf2f((ushort)hv[3]) * w0.w +
                 bf2f((ushort)hv[4]) * w1.x + bf2f((ushort)hv[5]) * w1.y +
                 bf2f((ushort)hv[6]) * w1.z + bf2f((ushort)hv[7]) * w1.w;
        }
        s += __shfl_xor(s, 1);
        if (hf == 0) zbuf[r][cc] = tanhf(s + eb3[cc]);
    }
    __syncthreads();

    // ---- SINDy Euler integration: registers + shfl, no barriers in loop ----
    if (tid < ROWS * LD) {
        const int r = tid >> 3, c = tid & 7;
        const float dt = logdt[row0 + r] * (1.0f / NSTEPS);
        float xr[NT];
#pragma unroll
        for (int i = 0; i < NT; ++i) xr[i] = Xi[i * LD + c];
        float zc = zbuf[r][c];
        const int lbase = (tid & 63) & ~7;
        for (int st = 0; st < NSTEPS; ++st) {
            float z[LD];
#pragma unroll
            for (int j = 0; j < LD; ++j) z[j] = __shfl(zc, lbase + j);
            float zd = xr[0];
#pragma unroll
            for (int j = 0; j < LD; ++j) zd += z[j] * xr[1 + j];
            int idx = 1 + LD;
#pragma unroll
            for (int i = 0; i < LD; ++i)
#pragma unroll
                for (int j2 = i; j2 < LD; ++j2) {
                    zd += z[i] * z[j2] * xr[idx];
                    ++idx;
                }
            zc += zd * dt;
        }
        zbuf[r][c] = zc;
    }
    __syncthreads();

    // ---- decoder layer 1: 8 -> 512 (fp32, C-layout), LN+SiLU in place ----
    {
        float wc[4][LD];
#pragma unroll
        for (int t = 0; t < 4; ++t) {
            const int c = w * 64 + t * 16 + lm;
#pragma unroll
            for (int k = 0; k < LD; ++k) wc[t][k] = dW1[k * H + c];
        }
        f32x4 acc[2][4];
#pragma unroll
        for (int mt = 0; mt < 2; ++mt)
#pragma unroll
            for (int r = 0; r < 4; ++r) {
                const int row = mt * 16 + q * 4 + r;
                float z[LD];
#pragma unroll
                for (int k = 0; k < LD; ++k) z[k] = zbuf[row][k];
#pragma unroll
                for (int t = 0; t < 4; ++t) {
                    float s = 0.f;
#pragma unroll
                    for (int k = 0; k < LD; ++k) s += z[k] * wc[t][k];
                    acc[mt][t][r] = s;
                }
            }
        ln_silu_store(acc, db1, dg1, dbe1, act, part1, part2, rowstat, w, lane, tid);
    }

    // ---- decoder layer 2: 512 -> 512 (MFMA), LN+SiLU in place ----
    {
        f32x4 acc[2][4];
        zero_acc(acc);
        gemm_mfma<H>(act, dW2T, acc, w, lane);
        ln_silu_store(acc, db2, dg2, dbe2, act, part1, part2, rowstat, w, lane, tid);
    }

    // ---- decoder layer 3: 512 -> 64 (MFMA) + bias, store fp32 ----
    {
        const int mt = w >> 2, nt = w & 3;
        f32x4 acc = (f32x4){0.f, 0.f, 0.f, 0.f};
#pragma unroll 4
        for (int kc = 0; kc < H / 32; ++kc) {
            const int k0 = kc * 32 + q * 8;
            short8 a = *(const short8*)&act[mt * 16 + lm][k0];
            short8 b = *(const short8*)&dW3T[(nt * 16 + lm) * H + k0];
            acc = __builtin_amdgcn_mfma_f32_16x16x32_bf16(a, b, acc, 0, 0, 0);
        }
        const int c = nt * 16 + lm;
        const float bb = db3[c];
#pragma unroll
        for (int r = 0; r < 4; ++r) {
            const int row = mt * 16 + q * 4 + r;
            out[(row0 + row) * NX + c] = acc[r] + bb;
        }
    }
}

// =================== fallback (fp32) if ws too small ===================
#define FB_R 16
#define FB_STRIDE 520
#define FB_NT 256

__device__ __forceinline__ void fb_ln_silu(float buf[FB_R][FB_STRIDE],
                                           const float* __restrict__ g,
                                           const float* __restrict__ be, int t) {
    const int r = t >> 4, lane = t & 15;
    float s1 = 0.f, s2 = 0.f;
#pragma unroll
    for (int j = 0; j < H / 16; ++j) {
        float v = buf[r][lane + 16 * j];
        s1 += v; s2 += v * v;
    }
#pragma unroll
    for (int m = 8; m >= 1; m >>= 1) {
        s1 += __shfl_xor(s1, m, 16);
        s2 += __shfl_xor(s2, m, 16);
    }
    const float mean = s1 * (1.0f / H);
    const float var = s2 * (1.0f / H) - mean * mean;
    const float rstd = rsqrtf(var + 1e-5f);
#pragma unroll
    for (int j = 0; j < H / 16; ++j) {
        const int c = lane + 16 * j;
        float v = buf[r][c];
        buf[r][c] = silu_f((v - mean) * rstd * g[c] + be[c]);
    }
}

template <int K>
__device__ __forceinline__ void fb_gemmK(const float in[FB_R][FB_STRIDE], float out[FB_R][FB_STRIDE],
                                         const float* __restrict__ W,
                                         const float* __restrict__ b, int t) {
    const int c0 = t, c1 = t + 256;
    float acc0[FB_R], acc1[FB_R];
#pragma unroll
    for (int r = 0; r < FB_R; ++r) { acc0[r] = 0.f; acc1[r] = 0.f; }
    for (int k = 0; k < K; k += 4) {
        const float w00 = W[(k + 0) * H + c0], w10 = W[(k + 0) * H + c1];
        const float w01 = W[(k + 1) * H + c0], w11 = W[(k + 1) * H + c1];
        const float w02 = W[(k + 2) * H + c0], w12 = W[(k + 2) * H + c1];
        const float w03 = W[(k + 3) * H + c0], w13 = W[(k + 3) * H + c1];
#pragma unroll
        for (int r = 0; r < FB_R; ++r) {
            const float4 h = *(const float4*)&in[r][k];
            acc0[r] += h.x * w00 + h.y * w01 + h.z * w02 + h.w * w03;
            acc1[r] += h.x * w10 + h.y * w11 + h.z * w12 + h.w * w13;
        }
    }
    const float b0 = b[c0], b1 = b[c1];
#pragma unroll
    for (int r = 0; r < FB_R; ++r) {
        out[r][c0] = acc0[r] + b0;
        out[r][c1] = acc1[r] + b1;
    }
}

__global__ __launch_bounds__(FB_NT, 2) void sindy_fallback_kernel(
    const float* __restrict__ x0, const float* __restrict__ logdt,
    const float* __restrict__ eW1, const float* __restrict__ eb1,
    const float* __restrict__ eg1, const float* __restrict__ ebe1,
    const float* __restrict__ eW2, const float* __restrict__ eb2,
    const float* __restrict__ eg2, const float* __restrict__ ebe2,
    const float* __restrict__ eW3, const float* __restrict__ eb3,
    const float* __restrict__ dW1, const float* __restrict__ db1,
    const float* __restrict__ dg1, const float* __restrict__ dbe1,
    const float* __restrict__ dW2, const float* __restrict__ db2,
    const float* __restrict__ dg2, const float* __restrict__ dbe2,
    const float* __restrict__ dW3, const float* __restrict__ db3,
    const float* __restrict__ Xi, float* __restrict__ out) {
    __shared__ float sA[FB_R][FB_STRIDE];
    __shared__ float sB[FB_R][FB_STRIDE];
    __shared__ float zbuf[FB_R][LD];
    __shared__ float dtb[FB_R];
    __shared__ float xis[NT * LD];

    const int t = threadIdx.x;
    const int row0 = blockIdx.x * FB_R;

    for (int i = t; i < NT * LD; i += FB_NT) xis[i] = Xi[i];
    if (t < FB_R) dtb[t] = logdt[row0 + t] * (1.0f / NSTEPS);
    {
        const int r = t >> 4, k4 = (t & 15) * 4;
        *(float4*)&sB[r][k4] = *(const float4*)&x0[(row0 + r) * NX + k4];
    }
    __syncthreads();
    fb_gemmK<NX>(sB, sA, eW1, eb1, t);
    __syncthreads();
    fb_ln_silu(sA, eg1, ebe1, t);
    __syncthreads();
    fb_gemmK<H>(sA, sB, eW2, eb2, t);
    __syncthreads();
    fb_ln_silu(sB, eg2, ebe2, t);
    __syncthreads();
    if (t < FB_R * LD) {
        const int r = t >> 3, c = t & 7;
        float acc = 0.f;
        for (int k = 0; k < H; k += 4) {
            const float4 h = *(const float4*)&sB[r][k];
            acc += h.x * eW3[(k + 0) * LD + c] + h.y * eW3[(k + 1) * LD + c] +
                   h.z * eW3[(k + 2) * LD + c] + h.w * eW3[(k + 3) * LD + c];
        }
        zbuf[r][c] = tanhf(acc + eb3[c]);
    }
    __syncthreads();
    for (int s = 0; s < NSTEPS; ++s) {
        float zn = 0.f;
        const int r = t >> 3, c = t & 7;
        if (t < FB_R * LD) {
            float z[LD];
#pragma unroll
            for (int j = 0; j < LD; ++j) z[j] = zbuf[r][j];
            float zd = xis[c];
#pragma unroll
            for (int j = 0; j < LD; ++j) zd += z[j] * xis[(1 + j) * LD + c];
            int idx = 1 + LD;
#pragma unroll
            for (int i = 0; i < LD; ++i)
#pragma unroll
                for (int j = i; j < LD; ++j) {
                    zd += z[i] * z[j] * xis[idx * LD + c];
                    ++idx;
                }
            zn = z[c] + zd * dtb[r];
        }
        __syncthreads();
        if (t < FB_R * LD) zbuf[r][c] = zn;
        __syncthreads();
    }
    {
        const int c0 = t, c1 = t + 256;
        float acc0[FB_R], acc1[FB_R];
#pragma unroll
        for (int r = 0; r < FB_R; ++r) { acc0[r] = 0.f; acc1[r] = 0.f; }
#pragma unroll
        for (int k = 0; k < LD; ++k) {
            const float w0 = dW1[k * H + c0], w1 = dW1[k * H + c1];
#pragma unroll
            for (int r = 0; r < FB_R; ++r) {
                const float zv = zbuf[r][k];
                acc0[r] += zv * w0;
                acc1[r] += zv * w1;
            }
        }
        const float b0 = db1[c0], b1v = db1[c1];
#pragma unroll
        for (int r = 0; r < FB_R; ++r) {
            sA[r][c0] = acc0[r] + b0;
            sA[r][c1] = acc1[r] + b1v;
        }
    }
    __syncthreads();
    fb_ln_silu(sA, dg1, dbe1, t);
    __syncthreads();
    fb_gemmK<H>(sA, sB, dW2, db2, t);
    __syncthreads();
    fb_ln_silu(sB, dg2, dbe2, t);
    __syncthreads();
    {
        const int c = t & 63;
        const int rb = t >> 6;
        float acc[4] = {0.f, 0.f, 0.f, 0.f};
        for (int k = 0; k < H; k += 4) {
            const float w0 = dW3[(k + 0) * NX + c];
            const float w1 = dW3[(k + 1) * NX + c];
            const float w2 = dW3[(k + 2) * NX + c];
            const float w3 = dW3[(k + 3) * NX + c];
#pragma unroll
            for (int i = 0; i < 4; ++i) {
                const int r = rb + 4 * i;
                const float4 h = *(const float4*)&sB[r][k];
                acc[i] += h.x * w0 + h.y * w1 + h.z * w2 + h.w * w3;
            }
        }
        const float bb = db3[c];
#pragma unroll
        for (int i = 0; i < 4; ++i) {
            const int r = rb + 4 * i;
            out[(row0 + r) * NX + c] = acc[i] + bb;
        }
    }
}

extern "C" void kernel_launch(void* const* d_in, const int* in_sizes, int n_in,
                              void* d_out, int out_size, void* d_ws, size_t ws_size,
                              hipStream_t stream) {
    const float* x0    = (const float*)d_in[0];
    const float* logdt = (const float*)d_in[1];
    const float* eW1  = (const float*)d_in[4];
    const float* eb1  = (const float*)d_in[5];
    const float* eg1  = (const float*)d_in[6];
    const float* ebe1 = (const float*)d_in[7];
    const float* eW2  = (const float*)d_in[8];
    const float* eb2  = (const float*)d_in[9];
    const float* eg2  = (const float*)d_in[10];
    const float* ebe2 = (const float*)d_in[11];
    const float* eW3  = (const float*)d_in[12];
    const float* eb3  = (const float*)d_in[13];
    const float* dW1  = (const float*)d_in[14];
    const float* db1  = (const float*)d_in[15];
    const float* dg1  = (const float*)d_in[16];
    const float* dbe1 = (const float*)d_in[17];
    const float* dW2  = (const float*)d_in[18];
    const float* db2  = (const float*)d_in[19];
    const float* dg2  = (const float*)d_in[20];
    const float* dbe2 = (const float*)d_in[21];
    const float* dW3  = (const float*)d_in[22];
    const float* db3  = (const float*)d_in[23];
    const float* Xi   = (const float*)d_in[24];
    float* out = (float*)d_out;

    if (ws_size >= (size_t)WS_BYTES) {
        prep_weights<<<(WS_BF16_ELEMS + EW3T_ELEMS) / 256, 256, 0, stream>>>(
            eW1, eW2, dW2, dW3, eW3, d_ws);
        sindy_mfma_kernel<<<B_TOTAL / ROWS, NTH, 0, stream>>>(
            x0, logdt, eb1, eg1, ebe1, eb2, eg2, ebe2, eb3,
            dW1, db1, dg1, dbe1, db2, dg2, dbe2, db3, Xi, d_ws, out);
    } else {
        sindy_fallback_kernel<<<B_TOTAL / FB_R, FB_NT, 0, stream>>>(
            x0, logdt, eW1, eb1, eg1, ebe1, eW2, eb2, eg2, ebe2, eW3, eb3,
            dW1, db1, dg1, dbe1, dW2, db2, dg2, dbe2, dW3, db3, Xi, out);
    }
}

// Round 4
// 1022.849 us; speedup vs baseline: 1.0048x; 1.0048x over previous
//
#include <hip/hip_runtime.h>
#include <hip/hip_bf16.h>
#include <math.h>

#define B_TOTAL 131072
#define NX 64
#define H 512
#define LD 8
#define NT 45          // 1 + 8 + 36
#define NSTEPS 20

// ---- main MFMA kernel config ----
#define ROWS 32        // rows per block
#define NTH 512        // 8 waves
#define ASTR 520       // bf16 elems per act row (1040 B: 16B-aligned rows)

// ws layout: bf16 W^T sections, then fp32 eW3T
#define OFF_EW1T 0                    // [512][64] bf16
#define OFF_EW2T 32768                // [512][512] bf16
#define OFF_DW2T 294912               // [512][512] bf16
#define OFF_DW3T 557056               // [64][512] bf16
#define WS_BF16_ELEMS 589824
#define OFF_EW3T_F32 294912           // float index (= byte 1179648): [8][512] fp32
#define EW3T_ELEMS 4096
#define WS_BYTES (WS_BF16_ELEMS * 2 + EW3T_ELEMS * 4)

typedef __attribute__((ext_vector_type(8))) short short8;
typedef __attribute__((ext_vector_type(4))) float f32x4;

__device__ __forceinline__ ushort f2bf(float f) {
    union { float f; uint u; } v; v.f = f;
    uint u = v.u;
    u += 0x7fff + ((u >> 16) & 1);          // RNE
    return (ushort)(u >> 16);
}
__device__ __forceinline__ float bf2f(ushort s) {
    union { uint u; float f; } v; v.u = ((uint)s) << 16;
    return v.f;
}
__device__ __forceinline__ uint pkbf(float a, float b) {
    union { __hip_bfloat162 h; uint u; } v;
    v.h = __float22bfloat162_rn(make_float2(a, b));
    return v.u;
}
__device__ __forceinline__ float silu_f(float v) {
    return v / (1.0f + __expf(-v));
}

// ---------------- weight prep ----------------
__global__ void prep_weights(const float* __restrict__ eW1, const float* __restrict__ eW2,
                             const float* __restrict__ dW2, const float* __restrict__ dW3,
                             const float* __restrict__ eW3, void* __restrict__ wsv) {
    short* ws = (short*)wsv;
    float* wf = (float*)wsv;
    const int id = blockIdx.x * 256 + threadIdx.x;
    if (id < OFF_EW2T) {                               // eW1T[n][k], n<512, k<64
        const int n = id >> 6, k = id & 63;
        ws[id] = (short)f2bf(eW1[k * H + n]);
    } else if (id < OFF_DW2T) {                        // eW2T 512x512
        const int j = id - OFF_EW2T, n = j >> 9, k = j & 511;
        ws[id] = (short)f2bf(eW2[k * H + n]);
    } else if (id < OFF_DW3T) {                        // dW2T 512x512
        const int j = id - OFF_DW2T, n = j >> 9, k = j & 511;
        ws[id] = (short)f2bf(dW2[k * H + n]);
    } else if (id < WS_BF16_ELEMS) {                   // dW3T[n][k], n<64, k<512
        const int j = id - OFF_DW3T, n = j >> 9, k = j & 511;
        ws[id] = (short)f2bf(dW3[k * NX + n]);
    } else {                                           // eW3T fp32 [8][512]
        const int j = id - WS_BF16_ELEMS, n = j >> 9, k = j & 511;
        wf[OFF_EW3T_F32 + j] = eW3[k * LD + n];
    }
}

// ---------------- big GEMM: act[32][K] bf16 LDS @ WT bf16 global ----------------
template <int K>
__device__ __forceinline__ void gemm_mfma(const short (*act)[ASTR], const short* __restrict__ WT,
                                          f32x4 acc[2][4], int w, int lane) {
    const int lm = lane & 15, q = lane >> 4;
#pragma unroll 4
    for (int kc = 0; kc < K / 32; ++kc) {
        const int k0 = kc * 32 + q * 8;
        short8 a0 = *(const short8*)&act[lm][k0];
        short8 a1 = *(const short8*)&act[16 + lm][k0];
        short8 b0 = *(const short8*)&WT[(w * 64 + 0 * 16 + lm) * K + k0];
        short8 b1 = *(const short8*)&WT[(w * 64 + 1 * 16 + lm) * K + k0];
        short8 b2 = *(const short8*)&WT[(w * 64 + 2 * 16 + lm) * K + k0];
        short8 b3 = *(const short8*)&WT[(w * 64 + 3 * 16 + lm) * K + k0];
        acc[0][0] = __builtin_amdgcn_mfma_f32_16x16x32_bf16(a0, b0, acc[0][0], 0, 0, 0);
        acc[1][0] = __builtin_amdgcn_mfma_f32_16x16x32_bf16(a1, b0, acc[1][0], 0, 0, 0);
        acc[0][1] = __builtin_amdgcn_mfma_f32_16x16x32_bf16(a0, b1, acc[0][1], 0, 0, 0);
        acc[1][1] = __builtin_amdgcn_mfma_f32_16x16x32_bf16(a1, b1, acc[1][1], 0, 0, 0);
        acc[0][2] = __builtin_amdgcn_mfma_f32_16x16x32_bf16(a0, b2, acc[0][2], 0, 0, 0);
        acc[1][2] = __builtin_amdgcn_mfma_f32_16x16x32_bf16(a1, b2, acc[1][2], 0, 0, 0);
        acc[0][3] = __builtin_amdgcn_mfma_f32_16x16x32_bf16(a0, b3, acc[0][3], 0, 0, 0);
        acc[1][3] = __builtin_amdgcn_mfma_f32_16x16x32_bf16(a1, b3, acc[1][3], 0, 0, 0);
    }
}

__device__ __forceinline__ void zero_acc(f32x4 acc[2][4]) {
#pragma unroll
    for (int mt = 0; mt < 2; ++mt)
#pragma unroll
        for (int t = 0; t < 4; ++t) acc[mt][t] = (f32x4){0.f, 0.f, 0.f, 0.f};
}

// bias + LayerNorm + SiLU on C-layout accs, bf16 store IN PLACE into act.
// C-layout: value (row = mt*16 + q*4 + reg, col = w*64 + t*16 + lm).
__device__ __forceinline__ void ln_silu_store(f32x4 acc[2][4],
        const float* __restrict__ bias, const float* __restrict__ g, const float* __restrict__ be,
        short (*dst)[ASTR], float (*p1)[8], float (*p2)[8], float (*rstat)[2],
        int w, int lane, int tid) {
    const int lm = lane & 15, q = lane >> 4;
    float cb[4], cg[4], cbe[4];
#pragma unroll
    for (int t = 0; t < 4; ++t) {
        const int c = w * 64 + t * 16 + lm;
        cb[t] = bias[c]; cg[t] = g[c]; cbe[t] = be[c];
    }
    float s1[8], s2[8];
#pragma unroll
    for (int i = 0; i < 8; ++i) { s1[i] = 0.f; s2[i] = 0.f; }
#pragma unroll
    for (int mt = 0; mt < 2; ++mt)
#pragma unroll
        for (int t = 0; t < 4; ++t)
#pragma unroll
            for (int r = 0; r < 4; ++r) {
                float v = acc[mt][t][r] + cb[t];
                acc[mt][t][r] = v;
                s1[mt * 4 + r] += v;
                s2[mt * 4 + r] += v * v;
            }
#pragma unroll
    for (int m = 1; m < 16; m <<= 1) {
#pragma unroll
        for (int i = 0; i < 8; ++i) {
            s1[i] += __shfl_xor(s1[i], m);
            s2[i] += __shfl_xor(s2[i], m);
        }
    }
    if (lm == 0) {
#pragma unroll
        for (int i = 0; i < 8; ++i) {
            const int row = (i >> 2) * 16 + q * 4 + (i & 3);
            p1[row][w] = s1[i];
            p2[row][w] = s2[i];
        }
    }
    __syncthreads();     // also orders: all GEMM act reads done before writes below
    if (tid < ROWS) {
        float a = 0.f, b2 = 0.f;
#pragma unroll
        for (int j = 0; j < 8; ++j) { a += p1[tid][j]; b2 += p2[tid][j]; }
        const float mean = a * (1.0f / H);
        rstat[tid][0] = mean;
        rstat[tid][1] = rsqrtf(b2 * (1.0f / H) - mean * mean + 1e-5f);
    }
    __syncthreads();
#pragma unroll
    for (int mt = 0; mt < 2; ++mt) {
        const int rowb = mt * 16 + q * 4;
#pragma unroll
        for (int rp = 0; rp < 2; ++rp) {
            const int r0 = rp * 2;
            const float2 st0 = *(const float2*)rstat[rowb + r0];
            const float2 st1 = *(const float2*)rstat[rowb + r0 + 1];
#pragma unroll
            for (int t = 0; t < 4; ++t) {
                float v0 = (acc[mt][t][r0]     - st0.x) * st0.y * cg[t] + cbe[t];
                float v1 = (acc[mt][t][r0 + 1] - st1.x) * st1.y * cg[t] + cbe[t];
                const uint u = pkbf(silu_f(v0), silu_f(v1));
                const int col = w * 64 + t * 16 + lm;
                dst[rowb + r0][col]     = (short)(u & 0xffff);
                dst[rowb + r0 + 1][col] = (short)(u >> 16);
            }
        }
    }
    __syncthreads();
}

__global__ __launch_bounds__(NTH, 6) void sindy_mfma_kernel(
    const float* __restrict__ x0, const float* __restrict__ logdt,
    const float* __restrict__ eb1, const float* __restrict__ eg1, const float* __restrict__ ebe1,
    const float* __restrict__ eb2, const float* __restrict__ eg2, const float* __restrict__ ebe2,
    const float* __restrict__ eb3,
    const float* __restrict__ dW1, const float* __restrict__ db1,
    const float* __restrict__ dg1, const float* __restrict__ dbe1,
    const float* __restrict__ db2, const float* __restrict__ dg2, const float* __restrict__ dbe2,
    const float* __restrict__ db3, const float* __restrict__ Xi,
    const void* __restrict__ wsv, float* __restrict__ out) {
    __shared__ __align__(16) short act[ROWS][ASTR];
    __shared__ float part1[ROWS][8], part2[ROWS][8];
    __shared__ float rowstat[ROWS][2];
    __shared__ float zbuf[ROWS][LD];
    __shared__ float xis[NT * LD];     // Xi staged in LDS: [term][col] -> conflict-free

    const int tid = threadIdx.x;
    const int w = tid >> 6, lane = tid & 63;
    const int lm = lane & 15, q = lane >> 4;
    const int row0 = blockIdx.x * ROWS;

    const short* wsb = (const short*)wsv;
    const float* wsf = (const float*)wsv;
    const short* eW1T = wsb + OFF_EW1T;
    const short* eW2T = wsb + OFF_EW2T;
    const short* dW2T = wsb + OFF_DW2T;
    const short* dW3T = wsb + OFF_DW3T;
    const float* eW3T = wsf + OFF_EW3T_F32;

    // ---- stage Xi + x tile (fp32 -> bf16 LDS, packed cvt) ----
    if (tid < NT * LD) xis[tid] = Xi[tid];
    {
        const int r = tid >> 4, c4 = (tid & 15) * 4;
        const float4 v = *(const float4*)&x0[(row0 + r) * NX + c4];
        uint2 pv;
        pv.x = pkbf(v.x, v.y);
        pv.y = pkbf(v.z, v.w);
        *(uint2*)&act[r][c4] = pv;
    }
    __syncthreads();

    // ---- encoder layer 1: 64 -> 512 (MFMA), LN+SiLU in place ----
    {
        f32x4 acc[2][4];
        zero_acc(acc);
        gemm_mfma<NX>(act, eW1T, acc, w, lane);
        ln_silu_store(acc, eb1, eg1, ebe1, act, part1, part2, rowstat, w, lane, tid);
    }

    // ---- encoder layer 2: 512 -> 512 (MFMA), LN+SiLU in place ----
    {
        f32x4 acc[2][4];
        zero_acc(acc);
        gemm_mfma<H>(act, eW2T, acc, w, lane);
        ln_silu_store(acc, eb2, eg2, ebe2, act, part1, part2, rowstat, w, lane, tid);
    }

    // ---- encoder layer 3: 512 -> 8 (fp32 weights), tanh -> z0 ----
    // All 512 threads: (row, col, k-half); pairwise shfl combine.
    {
        const int r = tid >> 4, cc = (tid >> 1) & 7, hf = tid & 1;
        const float* wT = eW3T + cc * H + hf * 256;
        const short* arow = &act[r][hf * 256];
        float s = 0.f;
#pragma unroll 4
        for (int k = 0; k < 256; k += 8) {
            short8 hv = *(const short8*)&arow[k];
            float4 w0 = *(const float4*)&wT[k];
            float4 w1 = *(const float4*)&wT[k + 4];
            s += bf2f((ushort)hv[0]) * w0.x + bf2f((ushort)hv[1]) * w0.y +
                 bf2f((ushort)hv[2]) * w0.z + bf2f((ushort)hv[3]) * w0.w +
                 bf2f((ushort)hv[4]) * w1.x + bf2f((ushort)hv[5]) * w1.y +
                 bf2f((ushort)hv[6]) * w1.z + bf2f((ushort)hv[7]) * w1.w;
        }
        s += __shfl_xor(s, 1);
        if (hf == 0) zbuf[r][cc] = tanhf(s + eb3[cc]);
    }
    __syncthreads();

    // ---- SINDy Euler integration: Xi from LDS (broadcast reads), shfl z-exchange,
    //      no barriers, no big register arrays (avoids scratch spill) ----
    if (tid < ROWS * LD) {
        const int r = tid >> 3, c = tid & 7;
        const float dt = logdt[row0 + r] * (1.0f / NSTEPS);
        float zc = zbuf[r][c];
        const int lbase = (tid & 63) & ~7;
        for (int st = 0; st < NSTEPS; ++st) {
            float z[LD];
#pragma unroll
            for (int j = 0; j < LD; ++j) z[j] = __shfl(zc, lbase + j);
            float zd = xis[c];
#pragma unroll
            for (int j = 0; j < LD; ++j) zd += z[j] * xis[(1 + j) * LD + c];
            int idx = 1 + LD;
#pragma unroll
            for (int i = 0; i < LD; ++i)
#pragma unroll
                for (int j2 = i; j2 < LD; ++j2) {
                    zd += z[i] * z[j2] * xis[idx * LD + c];
                    ++idx;
                }
            zc += zd * dt;
        }
        zbuf[r][c] = zc;
    }
    __syncthreads();

    // ---- decoder layer 1: 8 -> 512 (fp32, C-layout), LN+SiLU in place ----
    {
        float wc[4][LD];
#pragma unroll
        for (int t = 0; t < 4; ++t) {
            const int c = w * 64 + t * 16 + lm;
#pragma unroll
            for (int k = 0; k < LD; ++k) wc[t][k] = dW1[k * H + c];
        }
        f32x4 acc[2][4];
#pragma unroll
        for (int mt = 0; mt < 2; ++mt)
#pragma unroll
            for (int r = 0; r < 4; ++r) {
                const int row = mt * 16 + q * 4 + r;
                float z[LD];
#pragma unroll
                for (int k = 0; k < LD; ++k) z[k] = zbuf[row][k];
#pragma unroll
                for (int t = 0; t < 4; ++t) {
                    float s = 0.f;
#pragma unroll
                    for (int k = 0; k < LD; ++k) s += z[k] * wc[t][k];
                    acc[mt][t][r] = s;
                }
            }
        ln_silu_store(acc, db1, dg1, dbe1, act, part1, part2, rowstat, w, lane, tid);
    }

    // ---- decoder layer 2: 512 -> 512 (MFMA), LN+SiLU in place ----
    {
        f32x4 acc[2][4];
        zero_acc(acc);
        gemm_mfma<H>(act, dW2T, acc, w, lane);
        ln_silu_store(acc, db2, dg2, dbe2, act, part1, part2, rowstat, w, lane, tid);
    }

    // ---- decoder layer 3: 512 -> 64 (MFMA) + bias, store fp32 ----
    {
        const int mt = w >> 2, nt = w & 3;
        f32x4 acc = (f32x4){0.f, 0.f, 0.f, 0.f};
#pragma unroll 4
        for (int kc = 0; kc < H / 32; ++kc) {
            const int k0 = kc * 32 + q * 8;
            short8 a = *(const short8*)&act[mt * 16 + lm][k0];
            short8 b = *(const short8*)&dW3T[(nt * 16 + lm) * H + k0];
            acc = __builtin_amdgcn_mfma_f32_16x16x32_bf16(a, b, acc, 0, 0, 0);
        }
        const int c = nt * 16 + lm;
        const float bb = db3[c];
#pragma unroll
        for (int r = 0; r < 4; ++r) {
            const int row = mt * 16 + q * 4 + r;
            out[(row0 + row) * NX + c] = acc[r] + bb;
        }
    }
}

// =================== fallback (fp32) if ws too small ===================
#define FB_R 16
#define FB_STRIDE 520
#define FB_NT 256

__device__ __forceinline__ void fb_ln_silu(float buf[FB_R][FB_STRIDE],
                                           const float* __restrict__ g,
                                           const float* __restrict__ be, int t) {
    const int r = t >> 4, lane = t & 15;
    float s1 = 0.f, s2 = 0.f;
#pragma unroll
    for (int j = 0; j < H / 16; ++j) {
        float v = buf[r][lane + 16 * j];
        s1 += v; s2 += v * v;
    }
#pragma unroll
    for (int m = 8; m >= 1; m >>= 1) {
        s1 += __shfl_xor(s1, m, 16);
        s2 += __shfl_xor(s2, m, 16);
    }
    const float mean = s1 * (1.0f / H);
    const float var = s2 * (1.0f / H) - mean * mean;
    const float rstd = rsqrtf(var + 1e-5f);
#pragma unroll
    for (int j = 0; j < H / 16; ++j) {
        const int c = lane + 16 * j;
        float v = buf[r][c];
        buf[r][c] = silu_f((v - mean) * rstd * g[c] + be[c]);
    }
}

template <int K>
__device__ __forceinline__ void fb_gemmK(const float in[FB_R][FB_STRIDE], float out[FB_R][FB_STRIDE],
                                         const float* __restrict__ W,
                                         const float* __restrict__ b, int t) {
    const int c0 = t, c1 = t + 256;
    float acc0[FB_R], acc1[FB_R];
#pragma unroll
    for (int r = 0; r < FB_R; ++r) { acc0[r] = 0.f; acc1[r] = 0.f; }
    for (int k = 0; k < K; k += 4) {
        const float w00 = W[(k + 0) * H + c0], w10 = W[(k + 0) * H + c1];
        const float w01 = W[(k + 1) * H + c0], w11 = W[(k + 1) * H + c1];
        const float w02 = W[(k + 2) * H + c0], w12 = W[(k + 2) * H + c1];
        const float w03 = W[(k + 3) * H + c0], w13 = W[(k + 3) * H + c1];
#pragma unroll
        for (int r = 0; r < FB_R; ++r) {
            const float4 h = *(const float4*)&in[r][k];
            acc0[r] += h.x * w00 + h.y * w01 + h.z * w02 + h.w * w03;
            acc1[r] += h.x * w10 + h.y * w11 + h.z * w12 + h.w * w13;
        }
    }
    const float b0 = b[c0], b1 = b[c1];
#pragma unroll
    for (int r = 0; r < FB_R; ++r) {
        out[r][c0] = acc0[r] + b0;
        out[r][c1] = acc1[r] + b1;
    }
}

__global__ __launch_bounds__(FB_NT, 2) void sindy_fallback_kernel(
    const float* __restrict__ x0, const float* __restrict__ logdt,
    const float* __restrict__ eW1, const float* __restrict__ eb1,
    const float* __restrict__ eg1, const float* __restrict__ ebe1,
    const float* __restrict__ eW2, const float* __restrict__ eb2,
    const float* __restrict__ eg2, const float* __restrict__ ebe2,
    const float* __restrict__ eW3, const float* __restrict__ eb3,
    const float* __restrict__ dW1, const float* __restrict__ db1,
    const float* __restrict__ dg1, const float* __restrict__ dbe1,
    const float* __restrict__ dW2, const float* __restrict__ db2,
    const float* __restrict__ dg2, const float* __restrict__ dbe2,
    const float* __restrict__ dW3, const float* __restrict__ db3,
    const float* __restrict__ Xi, float* __restrict__ out) {
    __shared__ float sA[FB_R][FB_STRIDE];
    __shared__ float sB[FB_R][FB_STRIDE];
    __shared__ float zbuf[FB_R][LD];
    __shared__ float dtb[FB_R];
    __shared__ float xis[NT * LD];

    const int t = threadIdx.x;
    const int row0 = blockIdx.x * FB_R;

    for (int i = t; i < NT * LD; i += FB_NT) xis[i] = Xi[i];
    if (t < FB_R) dtb[t] = logdt[row0 + t] * (1.0f / NSTEPS);
    {
        const int r = t >> 4, k4 = (t & 15) * 4;
        *(float4*)&sB[r][k4] = *(const float4*)&x0[(row0 + r) * NX + k4];
    }
    __syncthreads();
    fb_gemmK<NX>(sB, sA, eW1, eb1, t);
    __syncthreads();
    fb_ln_silu(sA, eg1, ebe1, t);
    __syncthreads();
    fb_gemmK<H>(sA, sB, eW2, eb2, t);
    __syncthreads();
    fb_ln_silu(sB, eg2, ebe2, t);
    __syncthreads();
    if (t < FB_R * LD) {
        const int r = t >> 3, c = t & 7;
        float acc = 0.f;
        for (int k = 0; k < H; k += 4) {
            const float4 h = *(const float4*)&sB[r][k];
            acc += h.x * eW3[(k + 0) * LD + c] + h.y * eW3[(k + 1) * LD + c] +
                   h.z * eW3[(k + 2) * LD + c] + h.w * eW3[(k + 3) * LD + c];
        }
        zbuf[r][c] = tanhf(acc + eb3[c]);
    }
    __syncthreads();
    for (int s = 0; s < NSTEPS; ++s) {
        float zn = 0.f;
        const int r = t >> 3, c = t & 7;
        if (t < FB_R * LD) {
            float z[LD];
#pragma unroll
            for (int j = 0; j < LD; ++j) z[j] = zbuf[r][j];
            float zd = xis[c];
#pragma unroll
            for (int j = 0; j < LD; ++j) zd += z[j] * xis[(1 + j) * LD + c];
            int idx = 1 + LD;
#pragma unroll
            for (int i = 0; i < LD; ++i)
#pragma unroll
                for (int j = i; j < LD; ++j) {
                    zd += z[i] * z[j] * xis[idx * LD + c];
                    ++idx;
                }
            zn = z[c] + zd * dtb[r];
        }
        __syncthreads();
        if (t < FB_R * LD) zbuf[r][c] = zn;
        __syncthreads();
    }
    {
        const int c0 = t, c1 = t + 256;
        float acc0[FB_R], acc1[FB_R];
#pragma unroll
        for (int r = 0; r < FB_R; ++r) { acc0[r] = 0.f; acc1[r] = 0.f; }
#pragma unroll
        for (int k = 0; k < LD; ++k) {
            const float w0 = dW1[k * H + c0], w1 = dW1[k * H + c1];
#pragma unroll
            for (int r = 0; r < FB_R; ++r) {
                const float zv = zbuf[r][k];
                acc0[r] += zv * w0;
                acc1[r] += zv * w1;
            }
        }
        const float b0 = db1[c0], b1v = db1[c1];
#pragma unroll
        for (int r = 0; r < FB_R; ++r) {
            sA[r][c0] = acc0[r] + b0;
            sA[r][c1] = acc1[r] + b1v;
        }
    }
    __syncthreads();
    fb_ln_silu(sA, dg1, dbe1, t);
    __syncthreads();
    fb_gemmK<H>(sA, sB, dW2, db2, t);
    __syncthreads();
    fb_ln_silu(sB, dg2, dbe2, t);
    __syncthreads();
    {
        const int c = t & 63;
        const int rb = t >> 6;
        float acc[4] = {0.f, 0.f, 0.f, 0.f};
        for (int k = 0; k < H; k += 4) {
            const float w0 = dW3[(k + 0) * NX + c];
            const float w1 = dW3[(k + 1) * NX + c];
            const float w2 = dW3[(k + 2) * NX + c];
            const float w3 = dW3[(k + 3) * NX + c];
#pragma unroll
            for (int i = 0; i < 4; ++i) {
                const int r = rb + 4 * i;
                const float4 h = *(const float4*)&sB[r][k];
                acc[i] += h.x * w0 + h.y * w1 + h.z * w2 + h.w * w3;
            }
        }
        const float bb = db3[c];
#pragma unroll
        for (int i = 0; i < 4; ++i) {
            const int r = rb + 4 * i;
            out[(row0 + r) * NX + c] = acc[i] + bb;
        }
    }
}

extern "C" void kernel_launch(void* const* d_in, const int* in_sizes, int n_in,
                              void* d_out, int out_size, void* d_ws, size_t ws_size,
                              hipStream_t stream) {
    const float* x0    = (const float*)d_in[0];
    const float* logdt = (const float*)d_in[1];
    const float* eW1  = (const float*)d_in[4];
    const float* eb1  = (const float*)d_in[5];
    const float* eg1  = (const float*)d_in[6];
    const float* ebe1 = (const float*)d_in[7];
    const float* eW2  = (const float*)d_in[8];
    const float* eb2  = (const float*)d_in[9];
    const float* eg2  = (const float*)d_in[10];
    const float* ebe2 = (const float*)d_in[11];
    const float* eW3  = (const float*)d_in[12];
    const float* eb3  = (const float*)d_in[13];
    const float* dW1  = (const float*)d_in[14];
    const float* db1  = (const float*)d_in[15];
    const float* dg1  = (const float*)d_in[16];
    const float* dbe1 = (const float*)d_in[17];
    const float* dW2  = (const float*)d_in[18];
    const float* db2  = (const float*)d_in[19];
    const float* dg2  = (const float*)d_in[20];
    const float* dbe2 = (const float*)d_in[21];
    const float* dW3  = (const float*)d_in[22];
    const float* db3  = (const float*)d_in[23];
    const float* Xi   = (const float*)d_in[24];
    float* out = (float*)d_out;

    if (ws_size >= (size_t)WS_BYTES) {
        prep_weights<<<(WS_BF16_ELEMS + EW3T_ELEMS) / 256, 256, 0, stream>>>(
            eW1, eW2, dW2, dW3, eW3, d_ws);
        sindy_mfma_kernel<<<B_TOTAL / ROWS, NTH, 0, stream>>>(
            x0, logdt, eb1, eg1, ebe1, eb2, eg2, ebe2, eb3,
            dW1, db1, dg1, dbe1, db2, dg2, dbe2, db3, Xi, d_ws, out);
    } else {
        sindy_fallback_kernel<<<B_TOTAL / FB_R, FB_NT, 0, stream>>>(
            x0, logdt, eW1, eb1, eg1, ebe1, eW2, eb2, eg2, ebe2, eW3, eb3,
            dW1, db1, dg1, dbe1, dW2, db2, dg2, dbe2, dW3, db3, Xi, out);
    }
}

// Round 5
// 992.953 us; speedup vs baseline: 1.0351x; 1.0301x over previous
//
#include <hip/hip_runtime.h>
#include <hip/hip_bf16.h>
#include <math.h>

#define B_TOTAL 131072
#define NX 64
#define H 512
#define LD 8
#define NT 45          // 1 + 8 + 36
#define NSTEPS 20

// ---- main MFMA kernel config ----
#define ROWS 32        // rows per block
#define NTH 512        // 8 waves
#define ASTR 520       // bf16 elems per act row (1040 B: 16B-aligned rows)

// ws layout: bf16 W^T sections, then fp32 eW3T
#define OFF_EW1T 0                    // [512][64] bf16
#define OFF_EW2T 32768                // [512][512] bf16
#define OFF_DW2T 294912               // [512][512] bf16
#define OFF_DW3T 557056               // [64][512] bf16
#define WS_BF16_ELEMS 589824
#define OFF_EW3T_F32 294912           // float index (= byte 1179648): [8][512] fp32
#define EW3T_ELEMS 4096
#define WS_BYTES (WS_BF16_ELEMS * 2 + EW3T_ELEMS * 4)

typedef __attribute__((ext_vector_type(8))) short short8;
typedef __attribute__((ext_vector_type(4))) float f32x4;

__device__ __forceinline__ ushort f2bf(float f) {
    union { float f; uint u; } v; v.f = f;
    uint u = v.u;
    u += 0x7fff + ((u >> 16) & 1);          // RNE
    return (ushort)(u >> 16);
}
__device__ __forceinline__ float bf2f(ushort s) {
    union { uint u; float f; } v; v.u = ((uint)s) << 16;
    return v.f;
}
__device__ __forceinline__ uint pkbf(float a, float b) {
    union { __hip_bfloat162 h; uint u; } v;
    v.h = __float22bfloat162_rn(make_float2(a, b));
    return v.u;
}
__device__ __forceinline__ float silu_f(float v) {
    return v / (1.0f + __expf(-v));
}

// ---------------- weight prep ----------------
__global__ void prep_weights(const float* __restrict__ eW1, const float* __restrict__ eW2,
                             const float* __restrict__ dW2, const float* __restrict__ dW3,
                             const float* __restrict__ eW3, void* __restrict__ wsv) {
    short* ws = (short*)wsv;
    float* wf = (float*)wsv;
    const int id = blockIdx.x * 256 + threadIdx.x;
    if (id < OFF_EW2T) {                               // eW1T[n][k], n<512, k<64
        const int n = id >> 6, k = id & 63;
        ws[id] = (short)f2bf(eW1[k * H + n]);
    } else if (id < OFF_DW2T) {                        // eW2T 512x512
        const int j = id - OFF_EW2T, n = j >> 9, k = j & 511;
        ws[id] = (short)f2bf(eW2[k * H + n]);
    } else if (id < OFF_DW3T) {                        // dW2T 512x512
        const int j = id - OFF_DW2T, n = j >> 9, k = j & 511;
        ws[id] = (short)f2bf(dW2[k * H + n]);
    } else if (id < WS_BF16_ELEMS) {                   // dW3T[n][k], n<64, k<512
        const int j = id - OFF_DW3T, n = j >> 9, k = j & 511;
        ws[id] = (short)f2bf(dW3[k * NX + n]);
    } else {                                           // eW3T fp32 [8][512]
        const int j = id - WS_BF16_ELEMS, n = j >> 9, k = j & 511;
        wf[OFF_EW3T_F32 + j] = eW3[k * LD + n];
    }
}

// ---------------- big GEMM: act[32][K] bf16 LDS @ WT bf16 global ----------------
// Depth-2 software pipeline on the B (weight) loads: load chunk kc+1 while
// MFMA-ing chunk kc. K/32 is even for all instantiations (2 and 16).
template <int K>
__device__ __forceinline__ void gemm_mfma(const short (*act)[ASTR], const short* __restrict__ WT,
                                          f32x4 acc[2][4], int w, int lane) {
    const int lm = lane & 15, q = lane >> 4;
    const short* wp = WT + (w * 64 + lm) * K + q * 8;
    short8 bA[4], bB[4];
#pragma unroll
    for (int t = 0; t < 4; ++t) bA[t] = *(const short8*)(wp + t * 16 * K);
#pragma unroll 1
    for (int kc = 0; kc < K / 32; kc += 2) {
        const int k0 = kc * 32 + q * 8;
        // prefetch chunk kc+1 into bB
#pragma unroll
        for (int t = 0; t < 4; ++t)
            bB[t] = *(const short8*)(wp + t * 16 * K + (kc + 1) * 32);
        {
            short8 a0 = *(const short8*)&act[lm][k0];
            short8 a1 = *(const short8*)&act[16 + lm][k0];
            acc[0][0] = __builtin_amdgcn_mfma_f32_16x16x32_bf16(a0, bA[0], acc[0][0], 0, 0, 0);
            acc[1][0] = __builtin_amdgcn_mfma_f32_16x16x32_bf16(a1, bA[0], acc[1][0], 0, 0, 0);
            acc[0][1] = __builtin_amdgcn_mfma_f32_16x16x32_bf16(a0, bA[1], acc[0][1], 0, 0, 0);
            acc[1][1] = __builtin_amdgcn_mfma_f32_16x16x32_bf16(a1, bA[1], acc[1][1], 0, 0, 0);
            acc[0][2] = __builtin_amdgcn_mfma_f32_16x16x32_bf16(a0, bA[2], acc[0][2], 0, 0, 0);
            acc[1][2] = __builtin_amdgcn_mfma_f32_16x16x32_bf16(a1, bA[2], acc[1][2], 0, 0, 0);
            acc[0][3] = __builtin_amdgcn_mfma_f32_16x16x32_bf16(a0, bA[3], acc[0][3], 0, 0, 0);
            acc[1][3] = __builtin_amdgcn_mfma_f32_16x16x32_bf16(a1, bA[3], acc[1][3], 0, 0, 0);
        }
        // prefetch chunk kc+2 into bA (if it exists)
        if (kc + 2 < K / 32) {
#pragma unroll
            for (int t = 0; t < 4; ++t)
                bA[t] = *(const short8*)(wp + t * 16 * K + (kc + 2) * 32);
        }
        {
            short8 a0 = *(const short8*)&act[lm][k0 + 32];
            short8 a1 = *(const short8*)&act[16 + lm][k0 + 32];
            acc[0][0] = __builtin_amdgcn_mfma_f32_16x16x32_bf16(a0, bB[0], acc[0][0], 0, 0, 0);
            acc[1][0] = __builtin_amdgcn_mfma_f32_16x16x32_bf16(a1, bB[0], acc[1][0], 0, 0, 0);
            acc[0][1] = __builtin_amdgcn_mfma_f32_16x16x32_bf16(a0, bB[1], acc[0][1], 0, 0, 0);
            acc[1][1] = __builtin_amdgcn_mfma_f32_16x16x32_bf16(a1, bB[1], acc[1][1], 0, 0, 0);
            acc[0][2] = __builtin_amdgcn_mfma_f32_16x16x32_bf16(a0, bB[2], acc[0][2], 0, 0, 0);
            acc[1][2] = __builtin_amdgcn_mfma_f32_16x16x32_bf16(a1, bB[2], acc[1][2], 0, 0, 0);
            acc[0][3] = __builtin_amdgcn_mfma_f32_16x16x32_bf16(a0, bB[3], acc[0][3], 0, 0, 0);
            acc[1][3] = __builtin_amdgcn_mfma_f32_16x16x32_bf16(a1, bB[3], acc[1][3], 0, 0, 0);
        }
    }
}

__device__ __forceinline__ void zero_acc(f32x4 acc[2][4]) {
#pragma unroll
    for (int mt = 0; mt < 2; ++mt)
#pragma unroll
        for (int t = 0; t < 4; ++t) acc[mt][t] = (f32x4){0.f, 0.f, 0.f, 0.f};
}

// bias + LayerNorm + SiLU on C-layout accs, bf16 store IN PLACE into act.
// C-layout: value (row = mt*16 + q*4 + reg, col = w*64 + t*16 + lm).
__device__ __forceinline__ void ln_silu_store(f32x4 acc[2][4],
        const float* __restrict__ bias, const float* __restrict__ g, const float* __restrict__ be,
        short (*dst)[ASTR], float (*p1)[8], float (*p2)[8], float (*rstat)[2],
        int w, int lane, int tid) {
    const int lm = lane & 15, q = lane >> 4;
    float cb[4], cg[4], cbe[4];
#pragma unroll
    for (int t = 0; t < 4; ++t) {
        const int c = w * 64 + t * 16 + lm;
        cb[t] = bias[c]; cg[t] = g[c]; cbe[t] = be[c];
    }
    float s1[8], s2[8];
#pragma unroll
    for (int i = 0; i < 8; ++i) { s1[i] = 0.f; s2[i] = 0.f; }
#pragma unroll
    for (int mt = 0; mt < 2; ++mt)
#pragma unroll
        for (int t = 0; t < 4; ++t)
#pragma unroll
            for (int r = 0; r < 4; ++r) {
                float v = acc[mt][t][r] + cb[t];
                acc[mt][t][r] = v;
                s1[mt * 4 + r] += v;
                s2[mt * 4 + r] += v * v;
            }
#pragma unroll
    for (int m = 1; m < 16; m <<= 1) {
#pragma unroll
        for (int i = 0; i < 8; ++i) {
            s1[i] += __shfl_xor(s1[i], m);
            s2[i] += __shfl_xor(s2[i], m);
        }
    }
    if (lm == 0) {
#pragma unroll
        for (int i = 0; i < 8; ++i) {
            const int row = (i >> 2) * 16 + q * 4 + (i & 3);
            p1[row][w] = s1[i];
            p2[row][w] = s2[i];
        }
    }
    __syncthreads();     // also orders: all GEMM act reads done before writes below
    if (tid < ROWS) {
        float a = 0.f, b2 = 0.f;
#pragma unroll
        for (int j = 0; j < 8; ++j) { a += p1[tid][j]; b2 += p2[tid][j]; }
        const float mean = a * (1.0f / H);
        rstat[tid][0] = mean;
        rstat[tid][1] = rsqrtf(b2 * (1.0f / H) - mean * mean + 1e-5f);
    }
    __syncthreads();
#pragma unroll
    for (int mt = 0; mt < 2; ++mt) {
        const int rowb = mt * 16 + q * 4;
#pragma unroll
        for (int rp = 0; rp < 2; ++rp) {
            const int r0 = rp * 2;
            const float2 st0 = *(const float2*)rstat[rowb + r0];
            const float2 st1 = *(const float2*)rstat[rowb + r0 + 1];
#pragma unroll
            for (int t = 0; t < 4; ++t) {
                float v0 = (acc[mt][t][r0]     - st0.x) * st0.y * cg[t] + cbe[t];
                float v1 = (acc[mt][t][r0 + 1] - st1.x) * st1.y * cg[t] + cbe[t];
                const uint u = pkbf(silu_f(v0), silu_f(v1));
                const int col = w * 64 + t * 16 + lm;
                dst[rowb + r0][col]     = (short)(u & 0xffff);
                dst[rowb + r0 + 1][col] = (short)(u >> 16);
            }
        }
    }
    __syncthreads();
}

__global__ __launch_bounds__(NTH, 4) void sindy_mfma_kernel(
    const float* __restrict__ x0, const float* __restrict__ logdt,
    const float* __restrict__ eb1, const float* __restrict__ eg1, const float* __restrict__ ebe1,
    const float* __restrict__ eb2, const float* __restrict__ eg2, const float* __restrict__ ebe2,
    const float* __restrict__ eb3,
    const float* __restrict__ dW1, const float* __restrict__ db1,
    const float* __restrict__ dg1, const float* __restrict__ dbe1,
    const float* __restrict__ db2, const float* __restrict__ dg2, const float* __restrict__ dbe2,
    const float* __restrict__ db3, const float* __restrict__ Xi,
    const void* __restrict__ wsv, float* __restrict__ out) {
    __shared__ __align__(16) short act[ROWS][ASTR];
    __shared__ float part1[ROWS][8], part2[ROWS][8];
    __shared__ float rowstat[ROWS][2];
    __shared__ float zbuf[ROWS][LD];
    __shared__ float xis[NT * LD];     // Xi staged in LDS: [term][col] -> conflict-free

    const int tid = threadIdx.x;
    const int w = tid >> 6, lane = tid & 63;
    const int lm = lane & 15, q = lane >> 4;
    const int row0 = blockIdx.x * ROWS;

    const short* wsb = (const short*)wsv;
    const float* wsf = (const float*)wsv;
    const short* eW1T = wsb + OFF_EW1T;
    const short* eW2T = wsb + OFF_EW2T;
    const short* dW2T = wsb + OFF_DW2T;
    const short* dW3T = wsb + OFF_DW3T;
    const float* eW3T = wsf + OFF_EW3T_F32;

    // ---- stage Xi + x tile (fp32 -> bf16 LDS, packed cvt) ----
    if (tid < NT * LD) xis[tid] = Xi[tid];
    {
        const int r = tid >> 4, c4 = (tid & 15) * 4;
        const float4 v = *(const float4*)&x0[(row0 + r) * NX + c4];
        uint2 pv;
        pv.x = pkbf(v.x, v.y);
        pv.y = pkbf(v.z, v.w);
        *(uint2*)&act[r][c4] = pv;
    }
    __syncthreads();

    // ---- encoder layer 1: 64 -> 512 (MFMA), LN+SiLU in place ----
    {
        f32x4 acc[2][4];
        zero_acc(acc);
        gemm_mfma<NX>(act, eW1T, acc, w, lane);
        ln_silu_store(acc, eb1, eg1, ebe1, act, part1, part2, rowstat, w, lane, tid);
    }

    // ---- encoder layer 2: 512 -> 512 (MFMA), LN+SiLU in place ----
    {
        f32x4 acc[2][4];
        zero_acc(acc);
        gemm_mfma<H>(act, eW2T, acc, w, lane);
        ln_silu_store(acc, eb2, eg2, ebe2, act, part1, part2, rowstat, w, lane, tid);
    }

    // ---- encoder layer 3: 512 -> 8 (fp32 weights), tanh -> z0 ----
    // All 512 threads: (row, col, k-half); pairwise shfl combine.
    {
        const int r = tid >> 4, cc = (tid >> 1) & 7, hf = tid & 1;
        const float* wT = eW3T + cc * H + hf * 256;
        const short* arow = &act[r][hf * 256];
        float s = 0.f;
#pragma unroll 4
        for (int k = 0; k < 256; k += 8) {
            short8 hv = *(const short8*)&arow[k];
            float4 w0 = *(const float4*)&wT[k];
            float4 w1 = *(const float4*)&wT[k + 4];
            s += bf2f((ushort)hv[0]) * w0.x + bf2f((ushort)hv[1]) * w0.y +
                 bf2f((ushort)hv[2]) * w0.z + bf2f((ushort)hv[3]) * w0.w +
                 bf2f((ushort)hv[4]) * w1.x + bf2f((ushort)hv[5]) * w1.y +
                 bf2f((ushort)hv[6]) * w1.z + bf2f((ushort)hv[7]) * w1.w;
        }
        s += __shfl_xor(s, 1);
        if (hf == 0) zbuf[r][cc] = tanhf(s + eb3[cc]);
    }
    __syncthreads();

    // ---- SINDy Euler integration: Xi from LDS (broadcast reads), shfl z-exchange,
    //      no barriers, no big register arrays ----
    if (tid < ROWS * LD) {
        const int r = tid >> 3, c = tid & 7;
        const float dt = logdt[row0 + r] * (1.0f / NSTEPS);
        float zc = zbuf[r][c];
        const int lbase = (tid & 63) & ~7;
        for (int st = 0; st < NSTEPS; ++st) {
            float z[LD];
#pragma unroll
            for (int j = 0; j < LD; ++j) z[j] = __shfl(zc, lbase + j);
            float zd = xis[c];
#pragma unroll
            for (int j = 0; j < LD; ++j) zd += z[j] * xis[(1 + j) * LD + c];
            int idx = 1 + LD;
#pragma unroll
            for (int i = 0; i < LD; ++i)
#pragma unroll
                for (int j2 = i; j2 < LD; ++j2) {
                    zd += z[i] * z[j2] * xis[idx * LD + c];
                    ++idx;
                }
            zc += zd * dt;
        }
        zbuf[r][c] = zc;
    }
    __syncthreads();

    // ---- decoder layer 1: 8 -> 512 (fp32, C-layout), LN+SiLU in place ----
    {
        float wc[4][LD];
#pragma unroll
        for (int t = 0; t < 4; ++t) {
            const int c = w * 64 + t * 16 + lm;
#pragma unroll
            for (int k = 0; k < LD; ++k) wc[t][k] = dW1[k * H + c];
        }
        f32x4 acc[2][4];
#pragma unroll
        for (int mt = 0; mt < 2; ++mt)
#pragma unroll
            for (int r = 0; r < 4; ++r) {
                const int row = mt * 16 + q * 4 + r;
                float z[LD];
#pragma unroll
                for (int k = 0; k < LD; ++k) z[k] = zbuf[row][k];
#pragma unroll
                for (int t = 0; t < 4; ++t) {
                    float s = 0.f;
#pragma unroll
                    for (int k = 0; k < LD; ++k) s += z[k] * wc[t][k];
                    acc[mt][t][r] = s;
                }
            }
        ln_silu_store(acc, db1, dg1, dbe1, act, part1, part2, rowstat, w, lane, tid);
    }

    // ---- decoder layer 2: 512 -> 512 (MFMA), LN+SiLU in place ----
    {
        f32x4 acc[2][4];
        zero_acc(acc);
        gemm_mfma<H>(act, dW2T, acc, w, lane);
        ln_silu_store(acc, db2, dg2, dbe2, act, part1, part2, rowstat, w, lane, tid);
    }

    // ---- decoder layer 3: 512 -> 64 (MFMA) + bias, store fp32 ----
    {
        const int mt = w >> 2, nt = w & 3;
        f32x4 acc = (f32x4){0.f, 0.f, 0.f, 0.f};
#pragma unroll 4
        for (int kc = 0; kc < H / 32; ++kc) {
            const int k0 = kc * 32 + q * 8;
            short8 a = *(const short8*)&act[mt * 16 + lm][k0];
            short8 b = *(const short8*)&dW3T[(nt * 16 + lm) * H + k0];
            acc = __builtin_amdgcn_mfma_f32_16x16x32_bf16(a, b, acc, 0, 0, 0);
        }
        const int c = nt * 16 + lm;
        const float bb = db3[c];
#pragma unroll
        for (int r = 0; r < 4; ++r) {
            const int row = mt * 16 + q * 4 + r;
            out[(row0 + row) * NX + c] = acc[r] + bb;
        }
    }
}

// =================== fallback (fp32) if ws too small ===================
#define FB_R 16
#define FB_STRIDE 520
#define FB_NT 256

__device__ __forceinline__ void fb_ln_silu(float buf[FB_R][FB_STRIDE],
                                           const float* __restrict__ g,
                                           const float* __restrict__ be, int t) {
    const int r = t >> 4, lane = t & 15;
    float s1 = 0.f, s2 = 0.f;
#pragma unroll
    for (int j = 0; j < H / 16; ++j) {
        float v = buf[r][lane + 16 * j];
        s1 += v; s2 += v * v;
    }
#pragma unroll
    for (int m = 8; m >= 1; m >>= 1) {
        s1 += __shfl_xor(s1, m, 16);
        s2 += __shfl_xor(s2, m, 16);
    }
    const float mean = s1 * (1.0f / H);
    const float var = s2 * (1.0f / H) - mean * mean;
    const float rstd = rsqrtf(var + 1e-5f);
#pragma unroll
    for (int j = 0; j < H / 16; ++j) {
        const int c = lane + 16 * j;
        float v = buf[r][c];
        buf[r][c] = silu_f((v - mean) * rstd * g[c] + be[c]);
    }
}

template <int K>
__device__ __forceinline__ void fb_gemmK(const float in[FB_R][FB_STRIDE], float out[FB_R][FB_STRIDE],
                                         const float* __restrict__ W,
                                         const float* __restrict__ b, int t) {
    const int c0 = t, c1 = t + 256;
    float acc0[FB_R], acc1[FB_R];
#pragma unroll
    for (int r = 0; r < FB_R; ++r) { acc0[r] = 0.f; acc1[r] = 0.f; }
    for (int k = 0; k < K; k += 4) {
        const float w00 = W[(k + 0) * H + c0], w10 = W[(k + 0) * H + c1];
        const float w01 = W[(k + 1) * H + c0], w11 = W[(k + 1) * H + c1];
        const float w02 = W[(k + 2) * H + c0], w12 = W[(k + 2) * H + c1];
        const float w03 = W[(k + 3) * H + c0], w13 = W[(k + 3) * H + c1];
#pragma unroll
        for (int r = 0; r < FB_R; ++r) {
            const float4 h = *(const float4*)&in[r][k];
            acc0[r] += h.x * w00 + h.y * w01 + h.z * w02 + h.w * w03;
            acc1[r] += h.x * w10 + h.y * w11 + h.z * w12 + h.w * w13;
        }
    }
    const float b0 = b[c0], b1 = b[c1];
#pragma unroll
    for (int r = 0; r < FB_R; ++r) {
        out[r][c0] = acc0[r] + b0;
        out[r][c1] = acc1[r] + b1;
    }
}

__global__ __launch_bounds__(FB_NT, 2) void sindy_fallback_kernel(
    const float* __restrict__ x0, const float* __restrict__ logdt,
    const float* __restrict__ eW1, const float* __restrict__ eb1,
    const float* __restrict__ eg1, const float* __restrict__ ebe1,
    const float* __restrict__ eW2, const float* __restrict__ eb2,
    const float* __restrict__ eg2, const float* __restrict__ ebe2,
    const float* __restrict__ eW3, const float* __restrict__ eb3,
    const float* __restrict__ dW1, const float* __restrict__ db1,
    const float* __restrict__ dg1, const float* __restrict__ dbe1,
    const float* __restrict__ dW2, const float* __restrict__ db2,
    const float* __restrict__ dg2, const float* __restrict__ dbe2,
    const float* __restrict__ dW3, const float* __restrict__ db3,
    const float* __restrict__ Xi, float* __restrict__ out) {
    __shared__ float sA[FB_R][FB_STRIDE];
    __shared__ float sB[FB_R][FB_STRIDE];
    __shared__ float zbuf[FB_R][LD];
    __shared__ float dtb[FB_R];
    __shared__ float xis[NT * LD];

    const int t = threadIdx.x;
    const int row0 = blockIdx.x * FB_R;

    for (int i = t; i < NT * LD; i += FB_NT) xis[i] = Xi[i];
    if (t < FB_R) dtb[t] = logdt[row0 + t] * (1.0f / NSTEPS);
    {
        const int r = t >> 4, k4 = (t & 15) * 4;
        *(float4*)&sB[r][k4] = *(const float4*)&x0[(row0 + r) * NX + k4];
    }
    __syncthreads();
    fb_gemmK<NX>(sB, sA, eW1, eb1, t);
    __syncthreads();
    fb_ln_silu(sA, eg1, ebe1, t);
    __syncthreads();
    fb_gemmK<H>(sA, sB, eW2, eb2, t);
    __syncthreads();
    fb_ln_silu(sB, eg2, ebe2, t);
    __syncthreads();
    if (t < FB_R * LD) {
        const int r = t >> 3, c = t & 7;
        float acc = 0.f;
        for (int k = 0; k < H; k += 4) {
            const float4 h = *(const float4*)&sB[r][k];
            acc += h.x * eW3[(k + 0) * LD + c] + h.y * eW3[(k + 1) * LD + c] +
                   h.z * eW3[(k + 2) * LD + c] + h.w * eW3[(k + 3) * LD + c];
        }
        zbuf[r][c] = tanhf(acc + eb3[c]);
    }
    __syncthreads();
    for (int s = 0; s < NSTEPS; ++s) {
        float zn = 0.f;
        const int r = t >> 3, c = t & 7;
        if (t < FB_R * LD) {
            float z[LD];
#pragma unroll
            for (int j = 0; j < LD; ++j) z[j] = zbuf[r][j];
            float zd = xis[c];
#pragma unroll
            for (int j = 0; j < LD; ++j) zd += z[j] * xis[(1 + j) * LD + c];
            int idx = 1 + LD;
#pragma unroll
            for (int i = 0; i < LD; ++i)
#pragma unroll
                for (int j = i; j < LD; ++j) {
                    zd += z[i] * z[j] * xis[idx * LD + c];
                    ++idx;
                }
            zn = z[c] + zd * dtb[r];
        }
        __syncthreads();
        if (t < FB_R * LD) zbuf[r][c] = zn;
        __syncthreads();
    }
    {
        const int c0 = t, c1 = t + 256;
        float acc0[FB_R], acc1[FB_R];
#pragma unroll
        for (int r = 0; r < FB_R; ++r) { acc0[r] = 0.f; acc1[r] = 0.f; }
#pragma unroll
        for (int k = 0; k < LD; ++k) {
            const float w0 = dW1[k * H + c0], w1 = dW1[k * H + c1];
#pragma unroll
            for (int r = 0; r < FB_R; ++r) {
                const float zv = zbuf[r][k];
                acc0[r] += zv * w0;
                acc1[r] += zv * w1;
            }
        }
        const float b0 = db1[c0], b1v = db1[c1];
#pragma unroll
        for (int r = 0; r < FB_R; ++r) {
            sA[r][c0] = acc0[r] + b0;
            sA[r][c1] = acc1[r] + b1v;
        }
    }
    __syncthreads();
    fb_ln_silu(sA, dg1, dbe1, t);
    __syncthreads();
    fb_gemmK<H>(sA, sB, dW2, db2, t);
    __syncthreads();
    fb_ln_silu(sB, dg2, dbe2, t);
    __syncthreads();
    {
        const int c = t & 63;
        const int rb = t >> 6;
        float acc[4] = {0.f, 0.f, 0.f, 0.f};
        for (int k = 0; k < H; k += 4) {
            const float w0 = dW3[(k + 0) * NX + c];
            const float w1 = dW3[(k + 1) * NX + c];
            const float w2 = dW3[(k + 2) * NX + c];
            const float w3 = dW3[(k + 3) * NX + c];
#pragma unroll
            for (int i = 0; i < 4; ++i) {
                const int r = rb + 4 * i;
                const float4 h = *(const float4*)&sB[r][k];
                acc[i] += h.x * w0 + h.y * w1 + h.z * w2 + h.w * w3;
            }
        }
        const float bb = db3[c];
#pragma unroll
        for (int i = 0; i < 4; ++i) {
            const int r = rb + 4 * i;
            out[(row0 + r) * NX + c] = acc[i] + bb;
        }
    }
}

extern "C" void kernel_launch(void* const* d_in, const int* in_sizes, int n_in,
                              void* d_out, int out_size, void* d_ws, size_t ws_size,
                              hipStream_t stream) {
    const float* x0    = (const float*)d_in[0];
    const float* logdt = (const float*)d_in[1];
    const float* eW1  = (const float*)d_in[4];
    const float* eb1  = (const float*)d_in[5];
    const float* eg1  = (const float*)d_in[6];
    const float* ebe1 = (const float*)d_in[7];
    const float* eW2  = (const float*)d_in[8];
    const float* eb2  = (const float*)d_in[9];
    const float* eg2  = (const float*)d_in[10];
    const float* ebe2 = (const float*)d_in[11];
    const float* eW3  = (const float*)d_in[12];
    const float* eb3  = (const float*)d_in[13];
    const float* dW1  = (const float*)d_in[14];
    const float* db1  = (const float*)d_in[15];
    const float* dg1  = (const float*)d_in[16];
    const float* dbe1 = (const float*)d_in[17];
    const float* dW2  = (const float*)d_in[18];
    const float* db2  = (const float*)d_in[19];
    const float* dg2  = (const float*)d_in[20];
    const float* dbe2 = (const float*)d_in[21];
    const float* dW3  = (const float*)d_in[22];
    const float* db3  = (const float*)d_in[23];
    const float* Xi   = (const float*)d_in[24];
    float* out = (float*)d_out;

    if (ws_size >= (size_t)WS_BYTES) {
        prep_weights<<<(WS_BF16_ELEMS + EW3T_ELEMS) / 256, 256, 0, stream>>>(
            eW1, eW2, dW2, dW3, eW3, d_ws);
        sindy_mfma_kernel<<<B_TOTAL / ROWS, NTH, 0, stream>>>(
            x0, logdt, eb1, eg1, ebe1, eb2, eg2, ebe2, eb3,
            dW1, db1, dg1, dbe1, db2, dg2, dbe2, db3, Xi, d_ws, out);
    } else {
        sindy_fallback_kernel<<<B_TOTAL / FB_R, FB_NT, 0, stream>>>(
            x0, logdt, eW1, eb1, eg1, ebe1, eW2, eb2, eg2, ebe2, eW3, eb3,
            dW1, db1, dg1, dbe1, dW2, db2, dg2, dbe2, dW3, db3, Xi, out);
    }
}

// Round 6
// 992.303 us; speedup vs baseline: 1.0358x; 1.0007x over previous
//
#include <hip/hip_runtime.h>
#include <hip/hip_bf16.h>
#include <math.h>

#define B_TOTAL 131072
#define NX 64
#define H 512
#define LD 8
#define NT 45          // 1 + 8 + 36
#define NSTEPS 20

#define ROWS 32        // rows per block
#define NTH 512        // 8 waves
#define ASTR 520       // bf16 elems per act row (1040 B: 16B-aligned rows)

// ---- ws layout ----
// bf16 W^T sections, then fp32 eW3T, then (split path) two bf16 activation buffers.
#define OFF_EW1T 0                    // [512][64] bf16
#define OFF_EW2T 32768                // [512][512] bf16
#define OFF_DW2T 294912               // [512][512] bf16
#define OFF_DW3T 557056               // [64][512] bf16
#define WS_BF16_ELEMS 589824
#define OFF_EW3T_F32 294912           // float index (byte 1179648): [8][512] fp32
#define EW3T_ELEMS 4096
#define WS_BYTES (WS_BF16_ELEMS * 2 + EW3T_ELEMS * 4)      // 1,196,032
#define OFF_H1_B 1196032
#define H_BYTES ((size_t)B_TOTAL * H * 2)                   // 134,217,728
#define OFF_H2_B (OFF_H1_B + H_BYTES)
#define SPLIT_BYTES (OFF_H2_B + H_BYTES)                    // ~269.6 MB

typedef __attribute__((ext_vector_type(8))) short short8;
typedef __attribute__((ext_vector_type(4))) float f32x4;

__device__ __forceinline__ ushort f2bf(float f) {
    union { float f; uint u; } v; v.f = f;
    uint u = v.u;
    u += 0x7fff + ((u >> 16) & 1);          // RNE
    return (ushort)(u >> 16);
}
__device__ __forceinline__ float bf2f(ushort s) {
    union { uint u; float f; } v; v.u = ((uint)s) << 16;
    return v.f;
}
__device__ __forceinline__ uint pkbf(float a, float b) {
    union { __hip_bfloat162 h; uint u; } v;
    v.h = __float22bfloat162_rn(make_float2(a, b));
    return v.u;
}
__device__ __forceinline__ float silu_f(float v) {
    return v / (1.0f + __expf(-v));
}

// ---------------- weight prep ----------------
__global__ void prep_weights(const float* __restrict__ eW1, const float* __restrict__ eW2,
                             const float* __restrict__ dW2, const float* __restrict__ dW3,
                             const float* __restrict__ eW3, void* __restrict__ wsv) {
    short* ws = (short*)wsv;
    float* wf = (float*)wsv;
    const int id = blockIdx.x * 256 + threadIdx.x;
    if (id < OFF_EW2T) {                               // eW1T[n][k], n<512, k<64
        const int n = id >> 6, k = id & 63;
        ws[id] = (short)f2bf(eW1[k * H + n]);
    } else if (id < OFF_DW2T) {                        // eW2T 512x512
        const int j = id - OFF_EW2T, n = j >> 9, k = j & 511;
        ws[id] = (short)f2bf(eW2[k * H + n]);
    } else if (id < OFF_DW3T) {                        // dW2T 512x512
        const int j = id - OFF_DW2T, n = j >> 9, k = j & 511;
        ws[id] = (short)f2bf(dW2[k * H + n]);
    } else if (id < WS_BF16_ELEMS) {                   // dW3T[n][k], n<64, k<512
        const int j = id - OFF_DW3T, n = j >> 9, k = j & 511;
        ws[id] = (short)f2bf(dW3[k * NX + n]);
    } else {                                           // eW3T fp32 [8][512]
        const int j = id - WS_BF16_ELEMS, n = j >> 9, k = j & 511;
        wf[OFF_EW3T_F32 + j] = eW3[k * LD + n];
    }
}

// ---------------- shared device pieces ----------------
// global bf16 [.][512] tile -> LDS act (coalesced 16B, 256B/quarter-wave)
__device__ __forceinline__ void stage_tile(const short* __restrict__ src,
                                           short (*act)[ASTR], int row0, int tid) {
    const int r = tid >> 4, cb = (tid & 15) * 8;
#pragma unroll
    for (int p = 0; p < 4; ++p) {
        const int c = cb + p * 128;
        *(uint4*)&act[r][c] = *(const uint4*)&src[(size_t)(row0 + r) * H + c];
    }
}
__device__ __forceinline__ void copy_out_tile(const short (*act)[ASTR],
                                              short* __restrict__ dst, int row0, int tid) {
    const int r = tid >> 4, cb = (tid & 15) * 8;
#pragma unroll
    for (int p = 0; p < 4; ++p) {
        const int c = cb + p * 128;
        *(uint4*)&dst[(size_t)(row0 + r) * H + c] = *(const uint4*)&act[r][c];
    }
}

// big GEMM: act[32][K] bf16 LDS @ WT bf16 global (depth-2 B prefetch)
template <int K>
__device__ __forceinline__ void gemm_mfma(const short (*act)[ASTR], const short* __restrict__ WT,
                                          f32x4 acc[2][4], int w, int lane) {
    const int lm = lane & 15, q = lane >> 4;
    const short* wp = WT + (w * 64 + lm) * K + q * 8;
    short8 bA[4], bB[4];
#pragma unroll
    for (int t = 0; t < 4; ++t) bA[t] = *(const short8*)(wp + t * 16 * K);
#pragma unroll 1
    for (int kc = 0; kc < K / 32; kc += 2) {
        const int k0 = kc * 32 + q * 8;
#pragma unroll
        for (int t = 0; t < 4; ++t)
            bB[t] = *(const short8*)(wp + t * 16 * K + (kc + 1) * 32);
        {
            short8 a0 = *(const short8*)&act[lm][k0];
            short8 a1 = *(const short8*)&act[16 + lm][k0];
            acc[0][0] = __builtin_amdgcn_mfma_f32_16x16x32_bf16(a0, bA[0], acc[0][0], 0, 0, 0);
            acc[1][0] = __builtin_amdgcn_mfma_f32_16x16x32_bf16(a1, bA[0], acc[1][0], 0, 0, 0);
            acc[0][1] = __builtin_amdgcn_mfma_f32_16x16x32_bf16(a0, bA[1], acc[0][1], 0, 0, 0);
            acc[1][1] = __builtin_amdgcn_mfma_f32_16x16x32_bf16(a1, bA[1], acc[1][1], 0, 0, 0);
            acc[0][2] = __builtin_amdgcn_mfma_f32_16x16x32_bf16(a0, bA[2], acc[0][2], 0, 0, 0);
            acc[1][2] = __builtin_amdgcn_mfma_f32_16x16x32_bf16(a1, bA[2], acc[1][2], 0, 0, 0);
            acc[0][3] = __builtin_amdgcn_mfma_f32_16x16x32_bf16(a0, bA[3], acc[0][3], 0, 0, 0);
            acc[1][3] = __builtin_amdgcn_mfma_f32_16x16x32_bf16(a1, bA[3], acc[1][3], 0, 0, 0);
        }
        if (kc + 2 < K / 32) {
#pragma unroll
            for (int t = 0; t < 4; ++t)
                bA[t] = *(const short8*)(wp + t * 16 * K + (kc + 2) * 32);
        }
        {
            short8 a0 = *(const short8*)&act[lm][k0 + 32];
            short8 a1 = *(const short8*)&act[16 + lm][k0 + 32];
            acc[0][0] = __builtin_amdgcn_mfma_f32_16x16x32_bf16(a0, bB[0], acc[0][0], 0, 0, 0);
            acc[1][0] = __builtin_amdgcn_mfma_f32_16x16x32_bf16(a1, bB[0], acc[1][0], 0, 0, 0);
            acc[0][1] = __builtin_amdgcn_mfma_f32_16x16x32_bf16(a0, bB[1], acc[0][1], 0, 0, 0);
            acc[1][1] = __builtin_amdgcn_mfma_f32_16x16x32_bf16(a1, bB[1], acc[1][1], 0, 0, 0);
            acc[0][2] = __builtin_amdgcn_mfma_f32_16x16x32_bf16(a0, bB[2], acc[0][2], 0, 0, 0);
            acc[1][2] = __builtin_amdgcn_mfma_f32_16x16x32_bf16(a1, bB[2], acc[1][2], 0, 0, 0);
            acc[0][3] = __builtin_amdgcn_mfma_f32_16x16x32_bf16(a0, bB[3], acc[0][3], 0, 0, 0);
            acc[1][3] = __builtin_amdgcn_mfma_f32_16x16x32_bf16(a1, bB[3], acc[1][3], 0, 0, 0);
        }
    }
}

__device__ __forceinline__ void zero_acc(f32x4 acc[2][4]) {
#pragma unroll
    for (int mt = 0; mt < 2; ++mt)
#pragma unroll
        for (int t = 0; t < 4; ++t) acc[mt][t] = (f32x4){0.f, 0.f, 0.f, 0.f};
}

// bias + LayerNorm + SiLU on C-layout accs -> bf16 into act (in place).
__device__ __forceinline__ void ln_silu_store(f32x4 acc[2][4],
        const float* __restrict__ bias, const float* __restrict__ g, const float* __restrict__ be,
        short (*dst)[ASTR], float (*p1)[8], float (*p2)[8], float (*rstat)[2],
        int w, int lane, int tid) {
    const int lm = lane & 15, q = lane >> 4;
    float cb[4], cg[4], cbe[4];
#pragma unroll
    for (int t = 0; t < 4; ++t) {
        const int c = w * 64 + t * 16 + lm;
        cb[t] = bias[c]; cg[t] = g[c]; cbe[t] = be[c];
    }
    float s1[8], s2[8];
#pragma unroll
    for (int i = 0; i < 8; ++i) { s1[i] = 0.f; s2[i] = 0.f; }
#pragma unroll
    for (int mt = 0; mt < 2; ++mt)
#pragma unroll
        for (int t = 0; t < 4; ++t)
#pragma unroll
            for (int r = 0; r < 4; ++r) {
                float v = acc[mt][t][r] + cb[t];
                acc[mt][t][r] = v;
                s1[mt * 4 + r] += v;
                s2[mt * 4 + r] += v * v;
            }
#pragma unroll
    for (int m = 1; m < 16; m <<= 1) {
#pragma unroll
        for (int i = 0; i < 8; ++i) {
            s1[i] += __shfl_xor(s1[i], m);
            s2[i] += __shfl_xor(s2[i], m);
        }
    }
    if (lm == 0) {
#pragma unroll
        for (int i = 0; i < 8; ++i) {
            const int row = (i >> 2) * 16 + q * 4 + (i & 3);
            p1[row][w] = s1[i];
            p2[row][w] = s2[i];
        }
    }
    __syncthreads();
    if (tid < ROWS) {
        float a = 0.f, b2 = 0.f;
#pragma unroll
        for (int j = 0; j < 8; ++j) { a += p1[tid][j]; b2 += p2[tid][j]; }
        const float mean = a * (1.0f / H);
        rstat[tid][0] = mean;
        rstat[tid][1] = rsqrtf(b2 * (1.0f / H) - mean * mean + 1e-5f);
    }
    __syncthreads();
#pragma unroll
    for (int mt = 0; mt < 2; ++mt) {
        const int rowb = mt * 16 + q * 4;
#pragma unroll
        for (int rp = 0; rp < 2; ++rp) {
            const int r0 = rp * 2;
            const float2 st0 = *(const float2*)rstat[rowb + r0];
            const float2 st1 = *(const float2*)rstat[rowb + r0 + 1];
#pragma unroll
            for (int t = 0; t < 4; ++t) {
                float v0 = (acc[mt][t][r0]     - st0.x) * st0.y * cg[t] + cbe[t];
                float v1 = (acc[mt][t][r0 + 1] - st1.x) * st1.y * cg[t] + cbe[t];
                const uint u = pkbf(silu_f(v0), silu_f(v1));
                const int col = w * 64 + t * 16 + lm;
                dst[rowb + r0][col]     = (short)(u & 0xffff);
                dst[rowb + r0 + 1][col] = (short)(u >> 16);
            }
        }
    }
    __syncthreads();
}

// =================== split-path kernels ===================

// enc layer 1: x0 fp32 [B,64] -> h1 bf16 [B,512] (GEMM + LN + SiLU)
__global__ __launch_bounds__(NTH, 4) void k_enc1(
    const float* __restrict__ x0,
    const float* __restrict__ eb1, const float* __restrict__ eg1, const float* __restrict__ ebe1,
    const short* __restrict__ wsb, short* __restrict__ h1) {
    __shared__ __align__(16) short act[ROWS][ASTR];
    __shared__ float part1[ROWS][8], part2[ROWS][8];
    __shared__ float rowstat[ROWS][2];
    const int tid = threadIdx.x;
    const int w = tid >> 6, lane = tid & 63;
    const int row0 = blockIdx.x * ROWS;
    {
        const int r = tid >> 4, c4 = (tid & 15) * 4;
        const float4 v = *(const float4*)&x0[(row0 + r) * NX + c4];
        uint2 pv; pv.x = pkbf(v.x, v.y); pv.y = pkbf(v.z, v.w);
        *(uint2*)&act[r][c4] = pv;
    }
    __syncthreads();
    f32x4 acc[2][4];
    zero_acc(acc);
    gemm_mfma<NX>(act, wsb + OFF_EW1T, acc, w, lane);
    ln_silu_store(acc, eb1, eg1, ebe1, act, part1, part2, rowstat, w, lane, tid);
    copy_out_tile(act, h1, row0, tid);
}

// generic 512->512 GEMM + LN + SiLU: hin bf16 -> hout bf16
__global__ __launch_bounds__(NTH, 4) void k_gemm512(
    const short* __restrict__ hin, const short* __restrict__ WT,
    const float* __restrict__ bias, const float* __restrict__ g, const float* __restrict__ be,
    short* __restrict__ hout) {
    __shared__ __align__(16) short act[ROWS][ASTR];
    __shared__ float part1[ROWS][8], part2[ROWS][8];
    __shared__ float rowstat[ROWS][2];
    const int tid = threadIdx.x;
    const int w = tid >> 6, lane = tid & 63;
    const int row0 = blockIdx.x * ROWS;
    stage_tile(hin, act, row0, tid);
    __syncthreads();
    f32x4 acc[2][4];
    zero_acc(acc);
    gemm_mfma<H>(act, WT, acc, w, lane);
    ln_silu_store(acc, bias, g, be, act, part1, part2, rowstat, w, lane, tid);
    copy_out_tile(act, hout, row0, tid);
}

// middle: h2 -> z0 (enc3, tanh) -> 20 Euler steps -> dec1 + LN + SiLU -> h3
__global__ __launch_bounds__(NTH, 4) void k_mid(
    const short* __restrict__ h2, const float* __restrict__ logdt,
    const float* __restrict__ eb3,
    const float* __restrict__ dW1, const float* __restrict__ db1,
    const float* __restrict__ dg1, const float* __restrict__ dbe1,
    const float* __restrict__ Xi, const void* __restrict__ wsv,
    short* __restrict__ h3) {
    __shared__ __align__(16) short act[ROWS][ASTR];
    __shared__ float part1[ROWS][8], part2[ROWS][8];
    __shared__ float rowstat[ROWS][2];
    __shared__ float zbuf[ROWS][LD];
    __shared__ float xis[NT * LD];
    const int tid = threadIdx.x;
    const int w = tid >> 6, lane = tid & 63;
    const int lm = lane & 15, q = lane >> 4;
    const int row0 = blockIdx.x * ROWS;
    const float* eW3T = (const float*)wsv + OFF_EW3T_F32;

    if (tid < NT * LD) xis[tid] = Xi[tid];
    stage_tile(h2, act, row0, tid);
    __syncthreads();

    // enc3: 512 -> 8, tanh (fp32 weights), all 512 threads, pairwise shfl combine
    {
        const int r = tid >> 4, cc = (tid >> 1) & 7, hf = tid & 1;
        const float* wT = eW3T + cc * H + hf * 256;
        const short* arow = &act[r][hf * 256];
        float s = 0.f;
#pragma unroll 4
        for (int k = 0; k < 256; k += 8) {
            short8 hv = *(const short8*)&arow[k];
            float4 w0 = *(const float4*)&wT[k];
            float4 w1 = *(const float4*)&wT[k + 4];
            s += bf2f((ushort)hv[0]) * w0.x + bf2f((ushort)hv[1]) * w0.y +
                 bf2f((ushort)hv[2]) * w0.z + bf2f((ushort)hv[3]) * w0.w +
                 bf2f((ushort)hv[4]) * w1.x + bf2f((ushort)hv[5]) * w1.y +
                 bf2f((ushort)hv[6]) * w1.z + bf2f((ushort)hv[7]) * w1.w;
        }
        s += __shfl_xor(s, 1);
        if (hf == 0) zbuf[r][cc] = tanhf(s + eb3[cc]);
    }
    __syncthreads();

    // SINDy Euler: Xi from LDS (broadcast), shfl z-exchange, barrier-free
    if (tid < ROWS * LD) {
        const int r = tid >> 3, c = tid & 7;
        const float dt = logdt[row0 + r] * (1.0f / NSTEPS);
        float zc = zbuf[r][c];
        const int lbase = (tid & 63) & ~7;
        for (int st = 0; st < NSTEPS; ++st) {
            float z[LD];
#pragma unroll
            for (int j = 0; j < LD; ++j) z[j] = __shfl(zc, lbase + j);
            float zd = xis[c];
#pragma unroll
            for (int j = 0; j < LD; ++j) zd += z[j] * xis[(1 + j) * LD + c];
            int idx = 1 + LD;
#pragma unroll
            for (int i = 0; i < LD; ++i)
#pragma unroll
                for (int j2 = i; j2 < LD; ++j2) {
                    zd += z[i] * z[j2] * xis[idx * LD + c];
                    ++idx;
                }
            zc += zd * dt;
        }
        zbuf[r][c] = zc;
    }
    __syncthreads();

    // dec1: 8 -> 512 (fp32, C-layout) + LN + SiLU
    {
        float wc[4][LD];
#pragma unroll
        for (int t = 0; t < 4; ++t) {
            const int c = w * 64 + t * 16 + lm;
#pragma unroll
            for (int k = 0; k < LD; ++k) wc[t][k] = dW1[k * H + c];
        }
        f32x4 acc[2][4];
#pragma unroll
        for (int mt = 0; mt < 2; ++mt)
#pragma unroll
            for (int r = 0; r < 4; ++r) {
                const int row = mt * 16 + q * 4 + r;
                float z[LD];
#pragma unroll
                for (int k = 0; k < LD; ++k) z[k] = zbuf[row][k];
#pragma unroll
                for (int t = 0; t < 4; ++t) {
                    float s = 0.f;
#pragma unroll
                    for (int k = 0; k < LD; ++k) s += z[k] * wc[t][k];
                    acc[mt][t][r] = s;
                }
            }
        ln_silu_store(acc, db1, dg1, dbe1, act, part1, part2, rowstat, w, lane, tid);
    }
    copy_out_tile(act, h3, row0, tid);
}

// dec3: h4 bf16 [B,512] -> out fp32 [B,64]
__global__ __launch_bounds__(NTH, 4) void k_dec3(
    const short* __restrict__ h4, const short* __restrict__ wsb,
    const float* __restrict__ db3, float* __restrict__ out) {
    __shared__ __align__(16) short act[ROWS][ASTR];
    const int tid = threadIdx.x;
    const int w = tid >> 6, lane = tid & 63;
    const int lm = lane & 15, q = lane >> 4;
    const int row0 = blockIdx.x * ROWS;
    const short* dW3T = wsb + OFF_DW3T;
    stage_tile(h4, act, row0, tid);
    __syncthreads();
    const int mt = w >> 2, nt = w & 3;
    f32x4 acc = (f32x4){0.f, 0.f, 0.f, 0.f};
#pragma unroll 4
    for (int kc = 0; kc < H / 32; ++kc) {
        const int k0 = kc * 32 + q * 8;
        short8 a = *(const short8*)&act[mt * 16 + lm][k0];
        short8 b = *(const short8*)&dW3T[(nt * 16 + lm) * H + k0];
        acc = __builtin_amdgcn_mfma_f32_16x16x32_bf16(a, b, acc, 0, 0, 0);
    }
    const int c = nt * 16 + lm;
    const float bb = db3[c];
#pragma unroll
    for (int r = 0; r < 4; ++r) {
        const int row = mt * 16 + q * 4 + r;
        out[(row0 + row) * NX + c] = acc[r] + bb;
    }
}

// =================== tier-2: fused mega-kernel (R5) ===================
__global__ __launch_bounds__(NTH, 4) void sindy_mfma_kernel(
    const float* __restrict__ x0, const float* __restrict__ logdt,
    const float* __restrict__ eb1, const float* __restrict__ eg1, const float* __restrict__ ebe1,
    const float* __restrict__ eb2, const float* __restrict__ eg2, const float* __restrict__ ebe2,
    const float* __restrict__ eb3,
    const float* __restrict__ dW1, const float* __restrict__ db1,
    const float* __restrict__ dg1, const float* __restrict__ dbe1,
    const float* __restrict__ db2, const float* __restrict__ dg2, const float* __restrict__ dbe2,
    const float* __restrict__ db3, const float* __restrict__ Xi,
    const void* __restrict__ wsv, float* __restrict__ out) {
    __shared__ __align__(16) short act[ROWS][ASTR];
    __shared__ float part1[ROWS][8], part2[ROWS][8];
    __shared__ float rowstat[ROWS][2];
    __shared__ float zbuf[ROWS][LD];
    __shared__ float xis[NT * LD];

    const int tid = threadIdx.x;
    const int w = tid >> 6, lane = tid & 63;
    const int lm = lane & 15, q = lane >> 4;
    const int row0 = blockIdx.x * ROWS;

    const short* wsb = (const short*)wsv;
    const float* eW3T = (const float*)wsv + OFF_EW3T_F32;

    if (tid < NT * LD) xis[tid] = Xi[tid];
    {
        const int r = tid >> 4, c4 = (tid & 15) * 4;
        const float4 v = *(const float4*)&x0[(row0 + r) * NX + c4];
        uint2 pv; pv.x = pkbf(v.x, v.y); pv.y = pkbf(v.z, v.w);
        *(uint2*)&act[r][c4] = pv;
    }
    __syncthreads();
    {
        f32x4 acc[2][4];
        zero_acc(acc);
        gemm_mfma<NX>(act, wsb + OFF_EW1T, acc, w, lane);
        ln_silu_store(acc, eb1, eg1, ebe1, act, part1, part2, rowstat, w, lane, tid);
    }
    {
        f32x4 acc[2][4];
        zero_acc(acc);
        gemm_mfma<H>(act, wsb + OFF_EW2T, acc, w, lane);
        ln_silu_store(acc, eb2, eg2, ebe2, act, part1, part2, rowstat, w, lane, tid);
    }
    {
        const int r = tid >> 4, cc = (tid >> 1) & 7, hf = tid & 1;
        const float* wT = eW3T + cc * H + hf * 256;
        const short* arow = &act[r][hf * 256];
        float s = 0.f;
#pragma unroll 4
        for (int k = 0; k < 256; k += 8) {
            short8 hv = *(const short8*)&arow[k];
            float4 w0 = *(const float4*)&wT[k];
            float4 w1 = *(const float4*)&wT[k + 4];
            s += bf2f((ushort)hv[0]) * w0.x + bf2f((ushort)hv[1]) * w0.y +
                 bf2f((ushort)hv[2]) * w0.z + bf2f((ushort)hv[3]) * w0.w +
                 bf2f((ushort)hv[4]) * w1.x + bf2f((ushort)hv[5]) * w1.y +
                 bf2f((ushort)hv[6]) * w1.z + bf2f((ushort)hv[7]) * w1.w;
        }
        s += __shfl_xor(s, 1);
        if (hf == 0) zbuf[r][cc] = tanhf(s + eb3[cc]);
    }
    __syncthreads();
    if (tid < ROWS * LD) {
        const int r = tid >> 3, c = tid & 7;
        const float dt = logdt[row0 + r] * (1.0f / NSTEPS);
        float zc = zbuf[r][c];
        const int lbase = (tid & 63) & ~7;
        for (int st = 0; st < NSTEPS; ++st) {
            float z[LD];
#pragma unroll
            for (int j = 0; j < LD; ++j) z[j] = __shfl(zc, lbase + j);
            float zd = xis[c];
#pragma unroll
            for (int j = 0; j < LD; ++j) zd += z[j] * xis[(1 + j) * LD + c];
            int idx = 1 + LD;
#pragma unroll
            for (int i = 0; i < LD; ++i)
#pragma unroll
                for (int j2 = i; j2 < LD; ++j2) {
                    zd += z[i] * z[j2] * xis[idx * LD + c];
                    ++idx;
                }
            zc += zd * dt;
        }
        zbuf[r][c] = zc;
    }
    __syncthreads();
    {
        float wc[4][LD];
#pragma unroll
        for (int t = 0; t < 4; ++t) {
            const int c = w * 64 + t * 16 + lm;
#pragma unroll
            for (int k = 0; k < LD; ++k) wc[t][k] = dW1[k * H + c];
        }
        f32x4 acc[2][4];
#pragma unroll
        for (int mt = 0; mt < 2; ++mt)
#pragma unroll
            for (int r = 0; r < 4; ++r) {
                const int row = mt * 16 + q * 4 + r;
                float z[LD];
#pragma unroll
                for (int k = 0; k < LD; ++k) z[k] = zbuf[row][k];
#pragma unroll
                for (int t = 0; t < 4; ++t) {
                    float s = 0.f;
#pragma unroll
                    for (int k = 0; k < LD; ++k) s += z[k] * wc[t][k];
                    acc[mt][t][r] = s;
                }
            }
        ln_silu_store(acc, db1, dg1, dbe1, act, part1, part2, rowstat, w, lane, tid);
    }
    {
        f32x4 acc[2][4];
        zero_acc(acc);
        gemm_mfma<H>(act, wsb + OFF_DW2T, acc, w, lane);
        ln_silu_store(acc, db2, dg2, dbe2, act, part1, part2, rowstat, w, lane, tid);
    }
    {
        const int mt = w >> 2, nt = w & 3;
        f32x4 acc = (f32x4){0.f, 0.f, 0.f, 0.f};
#pragma unroll 4
        for (int kc = 0; kc < H / 32; ++kc) {
            const int k0 = kc * 32 + q * 8;
            short8 a = *(const short8*)&act[mt * 16 + lm][k0];
            short8 b = *(const short8*)&wsb[OFF_DW3T + (nt * 16 + lm) * H + k0];
            acc = __builtin_amdgcn_mfma_f32_16x16x32_bf16(a, b, acc, 0, 0, 0);
        }
        const int c = nt * 16 + lm;
        const float bb = db3[c];
#pragma unroll
        for (int r = 0; r < 4; ++r) {
            const int row = mt * 16 + q * 4 + r;
            out[(row0 + row) * NX + c] = acc[r] + bb;
        }
    }
}

// =================== tier-3: fp32 fallback ===================
#define FB_R 16
#define FB_STRIDE 520
#define FB_NT 256

__device__ __forceinline__ void fb_ln_silu(float buf[FB_R][FB_STRIDE],
                                           const float* __restrict__ g,
                                           const float* __restrict__ be, int t) {
    const int r = t >> 4, lane = t & 15;
    float s1 = 0.f, s2 = 0.f;
#pragma unroll
    for (int j = 0; j < H / 16; ++j) {
        float v = buf[r][lane + 16 * j];
        s1 += v; s2 += v * v;
    }
#pragma unroll
    for (int m = 8; m >= 1; m >>= 1) {
        s1 += __shfl_xor(s1, m, 16);
        s2 += __shfl_xor(s2, m, 16);
    }
    const float mean = s1 * (1.0f / H);
    const float var = s2 * (1.0f / H) - mean * mean;
    const float rstd = rsqrtf(var + 1e-5f);
#pragma unroll
    for (int j = 0; j < H / 16; ++j) {
        const int c = lane + 16 * j;
        float v = buf[r][c];
        buf[r][c] = silu_f((v - mean) * rstd * g[c] + be[c]);
    }
}

template <int K>
__device__ __forceinline__ void fb_gemmK(const float in[FB_R][FB_STRIDE], float out[FB_R][FB_STRIDE],
                                         const float* __restrict__ W,
                                         const float* __restrict__ b, int t) {
    const int c0 = t, c1 = t + 256;
    float acc0[FB_R], acc1[FB_R];
#pragma unroll
    for (int r = 0; r < FB_R; ++r) { acc0[r] = 0.f; acc1[r] = 0.f; }
    for (int k = 0; k < K; k += 4) {
        const float w00 = W[(k + 0) * H + c0], w10 = W[(k + 0) * H + c1];
        const float w01 = W[(k + 1) * H + c0], w11 = W[(k + 1) * H + c1];
        const float w02 = W[(k + 2) * H + c0], w12 = W[(k + 2) * H + c1];
        const float w03 = W[(k + 3) * H + c0], w13 = W[(k + 3) * H + c1];
#pragma unroll
        for (int r = 0; r < FB_R; ++r) {
            const float4 h = *(const float4*)&in[r][k];
            acc0[r] += h.x * w00 + h.y * w01 + h.z * w02 + h.w * w03;
            acc1[r] += h.x * w10 + h.y * w11 + h.z * w12 + h.w * w13;
        }
    }
    const float b0 = b[c0], b1 = b[c1];
#pragma unroll
    for (int r = 0; r < FB_R; ++r) {
        out[r][c0] = acc0[r] + b0;
        out[r][c1] = acc1[r] + b1;
    }
}

__global__ __launch_bounds__(FB_NT, 2) void sindy_fallback_kernel(
    const float* __restrict__ x0, const float* __restrict__ logdt,
    const float* __restrict__ eW1, const float* __restrict__ eb1,
    const float* __restrict__ eg1, const float* __restrict__ ebe1,
    const float* __restrict__ eW2, const float* __restrict__ eb2,
    const float* __restrict__ eg2, const float* __restrict__ ebe2,
    const float* __restrict__ eW3, const float* __restrict__ eb3,
    const float* __restrict__ dW1, const float* __restrict__ db1,
    const float* __restrict__ dg1, const float* __restrict__ dbe1,
    const float* __restrict__ dW2, const float* __restrict__ db2,
    const float* __restrict__ dg2, const float* __restrict__ dbe2,
    const float* __restrict__ dW3, const float* __restrict__ db3,
    const float* __restrict__ Xi, float* __restrict__ out) {
    __shared__ float sA[FB_R][FB_STRIDE];
    __shared__ float sB[FB_R][FB_STRIDE];
    __shared__ float zbuf[FB_R][LD];
    __shared__ float dtb[FB_R];
    __shared__ float xis[NT * LD];

    const int t = threadIdx.x;
    const int row0 = blockIdx.x * FB_R;

    for (int i = t; i < NT * LD; i += FB_NT) xis[i] = Xi[i];
    if (t < FB_R) dtb[t] = logdt[row0 + t] * (1.0f / NSTEPS);
    {
        const int r = t >> 4, k4 = (t & 15) * 4;
        *(float4*)&sB[r][k4] = *(const float4*)&x0[(row0 + r) * NX + k4];
    }
    __syncthreads();
    fb_gemmK<NX>(sB, sA, eW1, eb1, t);
    __syncthreads();
    fb_ln_silu(sA, eg1, ebe1, t);
    __syncthreads();
    fb_gemmK<H>(sA, sB, eW2, eb2, t);
    __syncthreads();
    fb_ln_silu(sB, eg2, ebe2, t);
    __syncthreads();
    if (t < FB_R * LD) {
        const int r = t >> 3, c = t & 7;
        float acc = 0.f;
        for (int k = 0; k < H; k += 4) {
            const float4 h = *(const float4*)&sB[r][k];
            acc += h.x * eW3[(k + 0) * LD + c] + h.y * eW3[(k + 1) * LD + c] +
                   h.z * eW3[(k + 2) * LD + c] + h.w * eW3[(k + 3) * LD + c];
        }
        zbuf[r][c] = tanhf(acc + eb3[c]);
    }
    __syncthreads();
    for (int s = 0; s < NSTEPS; ++s) {
        float zn = 0.f;
        const int r = t >> 3, c = t & 7;
        if (t < FB_R * LD) {
            float z[LD];
#pragma unroll
            for (int j = 0; j < LD; ++j) z[j] = zbuf[r][j];
            float zd = xis[c];
#pragma unroll
            for (int j = 0; j < LD; ++j) zd += z[j] * xis[(1 + j) * LD + c];
            int idx = 1 + LD;
#pragma unroll
            for (int i = 0; i < LD; ++i)
#pragma unroll
                for (int j = i; j < LD; ++j) {
                    zd += z[i] * z[j] * xis[idx * LD + c];
                    ++idx;
                }
            zn = z[c] + zd * dtb[r];
        }
        __syncthreads();
        if (t < FB_R * LD) zbuf[r][c] = zn;
        __syncthreads();
    }
    {
        const int c0 = t, c1 = t + 256;
        float acc0[FB_R], acc1[FB_R];
#pragma unroll
        for (int r = 0; r < FB_R; ++r) { acc0[r] = 0.f; acc1[r] = 0.f; }
#pragma unroll
        for (int k = 0; k < LD; ++k) {
            const float w0 = dW1[k * H + c0], w1 = dW1[k * H + c1];
#pragma unroll
            for (int r = 0; r < FB_R; ++r) {
                const float zv = zbuf[r][k];
                acc0[r] += zv * w0;
                acc1[r] += zv * w1;
            }
        }
        const float b0 = db1[c0], b1v = db1[c1];
#pragma unroll
        for (int r = 0; r < FB_R; ++r) {
            sA[r][c0] = acc0[r] + b0;
            sA[r][c1] = acc1[r] + b1v;
        }
    }
    __syncthreads();
    fb_ln_silu(sA, dg1, dbe1, t);
    __syncthreads();
    fb_gemmK<H>(sA, sB, dW2, db2, t);
    __syncthreads();
    fb_ln_silu(sB, dg2, dbe2, t);
    __syncthreads();
    {
        const int c = t & 63;
        const int rb = t >> 6;
        float acc[4] = {0.f, 0.f, 0.f, 0.f};
        for (int k = 0; k < H; k += 4) {
            const float w0 = dW3[(k + 0) * NX + c];
            const float w1 = dW3[(k + 1) * NX + c];
            const float w2 = dW3[(k + 2) * NX + c];
            const float w3 = dW3[(k + 3) * NX + c];
#pragma unroll
            for (int i = 0; i < 4; ++i) {
                const int r = rb + 4 * i;
                const float4 h = *(const float4*)&sB[r][k];
                acc[i] += h.x * w0 + h.y * w1 + h.z * w2 + h.w * w3;
            }
        }
        const float bb = db3[c];
#pragma unroll
        for (int i = 0; i < 4; ++i) {
            const int r = rb + 4 * i;
            out[(row0 + r) * NX + c] = acc[i] + bb;
        }
    }
}

extern "C" void kernel_launch(void* const* d_in, const int* in_sizes, int n_in,
                              void* d_out, int out_size, void* d_ws, size_t ws_size,
                              hipStream_t stream) {
    const float* x0    = (const float*)d_in[0];
    const float* logdt = (const float*)d_in[1];
    const float* eW1  = (const float*)d_in[4];
    const float* eb1  = (const float*)d_in[5];
    const float* eg1  = (const float*)d_in[6];
    const float* ebe1 = (const float*)d_in[7];
    const float* eW2  = (const float*)d_in[8];
    const float* eb2  = (const float*)d_in[9];
    const float* eg2  = (const float*)d_in[10];
    const float* ebe2 = (const float*)d_in[11];
    const float* eW3  = (const float*)d_in[12];
    const float* eb3  = (const float*)d_in[13];
    const float* dW1  = (const float*)d_in[14];
    const float* db1  = (const float*)d_in[15];
    const float* dg1  = (const float*)d_in[16];
    const float* dbe1 = (const float*)d_in[17];
    const float* dW2  = (const float*)d_in[18];
    const float* db2  = (const float*)d_in[19];
    const float* dg2  = (const float*)d_in[20];
    const float* dbe2 = (const float*)d_in[21];
    const float* dW3  = (const float*)d_in[22];
    const float* db3  = (const float*)d_in[23];
    const float* Xi   = (const float*)d_in[24];
    float* out = (float*)d_out;

    const int grid = B_TOTAL / ROWS;
    if (ws_size >= (size_t)SPLIT_BYTES) {
        prep_weights<<<(WS_BF16_ELEMS + EW3T_ELEMS) / 256, 256, 0, stream>>>(
            eW1, eW2, dW2, dW3, eW3, d_ws);
        const short* wsb = (const short*)d_ws;
        short* h1 = (short*)((char*)d_ws + OFF_H1_B);
        short* h2 = (short*)((char*)d_ws + OFF_H2_B);
        k_enc1<<<grid, NTH, 0, stream>>>(x0, eb1, eg1, ebe1, wsb, h1);
        k_gemm512<<<grid, NTH, 0, stream>>>(h1, wsb + OFF_EW2T, eb2, eg2, ebe2, h2);
        k_mid<<<grid, NTH, 0, stream>>>(h2, logdt, eb3, dW1, db1, dg1, dbe1, Xi, d_ws, h1);
        k_gemm512<<<grid, NTH, 0, stream>>>(h1, wsb + OFF_DW2T, db2, dg2, dbe2, h2);
        k_dec3<<<grid, NTH, 0, stream>>>(h2, wsb, db3, out);
    } else if (ws_size >= (size_t)WS_BYTES) {
        prep_weights<<<(WS_BF16_ELEMS + EW3T_ELEMS) / 256, 256, 0, stream>>>(
            eW1, eW2, dW2, dW3, eW3, d_ws);
        sindy_mfma_kernel<<<grid, NTH, 0, stream>>>(
            x0, logdt, eb1, eg1, ebe1, eb2, eg2, ebe2, eb3,
            dW1, db1, dg1, dbe1, db2, dg2, dbe2, db3, Xi, d_ws, out);
    } else {
        sindy_fallback_kernel<<<B_TOTAL / FB_R, FB_NT, 0, stream>>>(
            x0, logdt, eW1, eb1, eg1, ebe1, eW2, eb2, eg2, ebe2, eW3, eb3,
            dW1, db1, dg1, dbe1, dW2, db2, dg2, dbe2, dW3, db3, Xi, out);
    }
}